// Round 1
// baseline (630.520 us; speedup 1.0000x reference)
//
#include <hip/hip_runtime.h>
#include <math.h>

// TriangleAttentionStartingNode: B=1, N=256, C=128, H=4, AC=32, fp32.
// Pipeline: ln_nb -> proj_gemm(q,k,v,g) -> attn(flash, per (m,h)) -> out_gemm.
// Round 0: all-fp32 vector (no fp32 MFMA on CDNA4). Split-bf16 MFMA is a
// later-round optimization once baseline counters are in hand.

#define NRES 256
#define CCH  128
#define NROWS (NRES * NRES)          // 65536
#define FACTOR 0.17677669529663687f  // 1/sqrt(32)

__device__ __forceinline__ float dot4(float4 a, float4 b, float acc) {
    acc = fmaf(a.x, b.x, acc);
    acc = fmaf(a.y, b.y, acc);
    acc = fmaf(a.z, b.z, acc);
    acc = fmaf(a.w, b.w, acc);
    return acc;
}

// ---------------- LayerNorm + pair-bias nb (fused) ----------------
// One wave (64 lanes) per row of 128 channels. Also computes
// nb[h,i,j] = sum_c a[i,j,c]*w2d[c,h], stored transposed nbT[h][j][i]
// so the attention kernel's per-j reads are lane-coalesced.
__global__ __launch_bounds__(256) void ln_nb_kernel(
    const float* __restrict__ act, const float* __restrict__ ln_g,
    const float* __restrict__ ln_b, const float* __restrict__ w2d,
    float* __restrict__ a_out, float* __restrict__ nbT)
{
    const int wid = threadIdx.x >> 6;
    const int lane = threadIdx.x & 63;
    const int row = (blockIdx.x << 2) | wid;
    const float* __restrict__ x = act + (size_t)row * CCH;
    const int c0 = lane << 1;
    float x0 = x[c0], x1 = x[c0 + 1];
    float s = x0 + x1;
    float sq = fmaf(x0, x0, x1 * x1);
    #pragma unroll
    for (int o = 32; o > 0; o >>= 1) {
        s  += __shfl_xor(s, o, 64);
        sq += __shfl_xor(sq, o, 64);
    }
    float mu  = s * (1.0f / CCH);
    float var = fmaf(sq, 1.0f / CCH, -mu * mu);
    float rs  = rsqrtf(var + 1e-5f);
    float a0 = fmaf((x0 - mu) * rs, ln_g[c0],     ln_b[c0]);
    float a1 = fmaf((x1 - mu) * rs, ln_g[c0 + 1], ln_b[c0 + 1]);
    a_out[(size_t)row * CCH + c0]     = a0;
    a_out[(size_t)row * CCH + c0 + 1] = a1;
    // nb partials: w2d is [C][H] row-major
    float nb0 = fmaf(a0, w2d[c0 * 4 + 0], a1 * w2d[(c0 + 1) * 4 + 0]);
    float nb1 = fmaf(a0, w2d[c0 * 4 + 1], a1 * w2d[(c0 + 1) * 4 + 1]);
    float nb2 = fmaf(a0, w2d[c0 * 4 + 2], a1 * w2d[(c0 + 1) * 4 + 2]);
    float nb3 = fmaf(a0, w2d[c0 * 4 + 3], a1 * w2d[(c0 + 1) * 4 + 3]);
    #pragma unroll
    for (int o = 32; o > 0; o >>= 1) {
        nb0 += __shfl_xor(nb0, o, 64);
        nb1 += __shfl_xor(nb1, o, 64);
        nb2 += __shfl_xor(nb2, o, 64);
        nb3 += __shfl_xor(nb3, o, 64);
    }
    if (lane == 0) {
        const int i = row >> 8, j = row & 255;    // act row = i*256 + j
        const size_t o = (size_t)j * 256 + i;     // nbT[h][j][i]
        nbT[o]             = nb0;
        nbT[NROWS + o]     = nb1;
        nbT[2 * NROWS + o] = nb2;
        nbT[3 * NROWS + o] = nb3;
    }
}

// ---------------- projection GEMM: [65536,128] @ [128,128] x4 ----------------
// grid = (1024 row-blocks, 8): blockIdx.y -> (tensor = y>>1, col half = (y&1)*64).
// 64x64 tile, BK=64, 4x4 micro-tile per thread. as padded to 68 -> 2-way (free)
// LDS read conflicts; bs read as b128 2-way (free).
__global__ __launch_bounds__(256) void proj_gemm_kernel(
    const float* __restrict__ A,
    const float* __restrict__ wq, const float* __restrict__ wk,
    const float* __restrict__ wv, const float* __restrict__ wg,
    const float* __restrict__ bg,
    float* __restrict__ qb, float* __restrict__ kb,
    float* __restrict__ vb, float* __restrict__ gb)
{
    __shared__ float as[64][68];
    __shared__ float bs[64][64];
    const int t = threadIdx.x;
    const int rb = blockIdx.x;
    const int cb = blockIdx.y;
    const int tensor = cb >> 1;
    const int c0 = (cb & 1) << 6;
    const float* __restrict__ W =
        (tensor == 0) ? wq : (tensor == 1) ? wk : (tensor == 2) ? wv : wg;
    const int tr = t >> 4, tc = t & 15;
    const int r0 = rb << 6;
    float acc[4][4];
    #pragma unroll
    for (int u = 0; u < 4; ++u)
        #pragma unroll
        for (int w = 0; w < 4; ++w) acc[u][w] = 0.0f;

    for (int k0 = 0; k0 < CCH; k0 += 64) {
        __syncthreads();
        #pragma unroll
        for (int it = 0; it < 4; ++it) {
            int flat = t + (it << 8);
            int row = flat >> 4, q4i = flat & 15;
            *(float4*)&as[row][q4i << 2] =
                *(const float4*)&A[(size_t)(r0 + row) * CCH + k0 + (q4i << 2)];
            *(float4*)&bs[row][q4i << 2] =
                *(const float4*)&W[(size_t)(k0 + row) * CCH + c0 + (q4i << 2)];
        }
        __syncthreads();
        #pragma unroll 8
        for (int k = 0; k < 64; ++k) {
            float4 b4 = *(const float4*)&bs[k][tc << 2];
            #pragma unroll
            for (int u = 0; u < 4; ++u) {
                float av = as[(tr << 2) + u][k];
                acc[u][0] = fmaf(av, b4.x, acc[u][0]);
                acc[u][1] = fmaf(av, b4.y, acc[u][1]);
                acc[u][2] = fmaf(av, b4.z, acc[u][2]);
                acc[u][3] = fmaf(av, b4.w, acc[u][3]);
            }
        }
    }
    float* __restrict__ OUT =
        (tensor == 0) ? qb : (tensor == 1) ? kb : (tensor == 2) ? vb : gb;
    #pragma unroll
    for (int u = 0; u < 4; ++u) {
        int row = r0 + (tr << 2) + u;
        int c = c0 + (tc << 2);
        float o0 = acc[u][0], o1 = acc[u][1], o2 = acc[u][2], o3 = acc[u][3];
        if (tensor == 0) {
            o0 *= FACTOR; o1 *= FACTOR; o2 *= FACTOR; o3 *= FACTOR;
        } else if (tensor == 3) {
            o0 = 1.0f / (1.0f + __expf(-(o0 + bg[c])));
            o1 = 1.0f / (1.0f + __expf(-(o1 + bg[c + 1])));
            o2 = 1.0f / (1.0f + __expf(-(o2 + bg[c + 2])));
            o3 = 1.0f / (1.0f + __expf(-(o3 + bg[c + 3])));
        }
        *(float4*)&OUT[(size_t)row * CCH + c] = make_float4(o0, o1, o2, o3);
    }
}

// ---------------- attention (flash-style) ----------------
// One block per (m,h); 128 threads; thread t owns query rows t and t+128 so
// each broadcast K/V ds_read_b128 feeds 8 FMAs. K/V staged in 64-row LDS
// tiles; online softmax per row; gated output staged through LDS for
// coalesced stores.
__global__ __launch_bounds__(128) void attn_kernel(
    const float* __restrict__ qb, const float* __restrict__ kb,
    const float* __restrict__ vb, const float* __restrict__ gb,
    const float* __restrict__ mask, const float* __restrict__ nbT,
    float* __restrict__ gated)
{
    __shared__ float smem[64 * 36 * 2];   // K tile | V tile (also q/g staging)
    __shared__ float biasrow[256];
    const int t = threadIdx.x;
    const int mrow = blockIdx.x >> 2;
    const int h = blockIdx.x & 3;
    const size_t base = (size_t)mrow * 256 * CCH + h * 32;

    {
        float mv0 = mask[mrow * 256 + t];
        float mv1 = mask[mrow * 256 + t + 128];
        biasrow[t]       = 1e9f * (mv0 - 1.0f);
        biasrow[t + 128] = 1e9f * (mv1 - 1.0f);
    }

    // stage q (256 rows x 32) through LDS in two halves -> registers
    float4 q4[2][8];
    #pragma unroll
    for (int rr = 0; rr < 2; ++rr) {
        __syncthreads();
        #pragma unroll
        for (int it = 0; it < 8; ++it) {
            int flat = t + (it << 7);
            int row = flat >> 3, c4 = flat & 7;
            *(float4*)&smem[row * 36 + (c4 << 2)] =
                *(const float4*)&qb[base + (size_t)((rr << 7) + row) * CCH + (c4 << 2)];
        }
        __syncthreads();
        #pragma unroll
        for (int c4 = 0; c4 < 8; ++c4)
            q4[rr][c4] = *(const float4*)&smem[t * 36 + (c4 << 2)];
    }

    float4 acc[2][8];
    #pragma unroll
    for (int rr = 0; rr < 2; ++rr)
        #pragma unroll
        for (int c4 = 0; c4 < 8; ++c4)
            acc[rr][c4] = make_float4(0.f, 0.f, 0.f, 0.f);
    float rm0 = -1e30f, rm1 = -1e30f, l0 = 0.0f, l1 = 0.0f;
    const float* __restrict__ nbh = nbT + (size_t)h * NROWS;

    for (int tile = 0; tile < 4; ++tile) {
        const int jb = tile << 6;
        __syncthreads();
        #pragma unroll
        for (int it = 0; it < 4; ++it) {
            int flat = t + (it << 7);
            int row = flat >> 3, c4 = flat & 7;
            *(float4*)&smem[row * 36 + (c4 << 2)] =
                *(const float4*)&kb[base + (size_t)(jb + row) * CCH + (c4 << 2)];
            *(float4*)&smem[2304 + row * 36 + (c4 << 2)] =
                *(const float4*)&vb[base + (size_t)(jb + row) * CCH + (c4 << 2)];
        }
        __syncthreads();

        #pragma unroll 1
        for (int j0 = 0; j0 < 64; j0 += 8) {
            float s0[8], s1[8];
            #pragma unroll
            for (int jj = 0; jj < 8; ++jj) {
                const float* kp = &smem[(j0 + jj) * 36];
                float d0 = 0.0f, d1 = 0.0f;
                #pragma unroll
                for (int c4 = 0; c4 < 8; ++c4) {
                    float4 kk = *(const float4*)&kp[c4 << 2];
                    d0 = dot4(q4[0][c4], kk, d0);
                    d1 = dot4(q4[1][c4], kk, d1);
                }
                int j = jb + j0 + jj;
                float bb = biasrow[j];
                s0[jj] = d0 + bb + nbh[(size_t)j * 256 + t];
                s1[jj] = d1 + bb + nbh[(size_t)j * 256 + t + 128];
            }
            float cm0 = s0[0], cm1 = s1[0];
            #pragma unroll
            for (int jj = 1; jj < 8; ++jj) {
                cm0 = fmaxf(cm0, s0[jj]);
                cm1 = fmaxf(cm1, s1[jj]);
            }
            float mn0 = fmaxf(rm0, cm0), mn1 = fmaxf(rm1, cm1);
            float sc0 = __expf(rm0 - mn0), sc1 = __expf(rm1 - mn1);
            rm0 = mn0; rm1 = mn1;
            l0 *= sc0; l1 *= sc1;
            #pragma unroll
            for (int c4 = 0; c4 < 8; ++c4) {
                acc[0][c4].x *= sc0; acc[0][c4].y *= sc0;
                acc[0][c4].z *= sc0; acc[0][c4].w *= sc0;
                acc[1][c4].x *= sc1; acc[1][c4].y *= sc1;
                acc[1][c4].z *= sc1; acc[1][c4].w *= sc1;
            }
            #pragma unroll
            for (int jj = 0; jj < 8; ++jj) {
                float p0 = __expf(s0[jj] - mn0);
                float p1 = __expf(s1[jj] - mn1);
                l0 += p0; l1 += p1;
                const float* vp = &smem[2304 + (j0 + jj) * 36];
                #pragma unroll
                for (int c4 = 0; c4 < 8; ++c4) {
                    float4 vv = *(const float4*)&vp[c4 << 2];
                    acc[0][c4].x = fmaf(p0, vv.x, acc[0][c4].x);
                    acc[0][c4].y = fmaf(p0, vv.y, acc[0][c4].y);
                    acc[0][c4].z = fmaf(p0, vv.z, acc[0][c4].z);
                    acc[0][c4].w = fmaf(p0, vv.w, acc[0][c4].w);
                    acc[1][c4].x = fmaf(p1, vv.x, acc[1][c4].x);
                    acc[1][c4].y = fmaf(p1, vv.y, acc[1][c4].y);
                    acc[1][c4].z = fmaf(p1, vv.z, acc[1][c4].z);
                    acc[1][c4].w = fmaf(p1, vv.w, acc[1][c4].w);
                }
            }
        }
    }

    const float inv0 = 1.0f / l0, inv1 = 1.0f / l1;
    #pragma unroll
    for (int rr = 0; rr < 2; ++rr) {
        const float inv = rr ? inv1 : inv0;
        __syncthreads();
        #pragma unroll
        for (int it = 0; it < 8; ++it) {   // stage g half
            int flat = t + (it << 7);
            int row = flat >> 3, c4 = flat & 7;
            *(float4*)&smem[row * 36 + (c4 << 2)] =
                *(const float4*)&gb[base + (size_t)((rr << 7) + row) * CCH + (c4 << 2)];
        }
        __syncthreads();
        #pragma unroll
        for (int c4 = 0; c4 < 8; ++c4) {
            float4 gg = *(const float4*)&smem[t * 36 + (c4 << 2)];
            float4 av = acc[rr][c4];
            float4 ov;
            ov.x = av.x * inv * gg.x;
            ov.y = av.y * inv * gg.y;
            ov.z = av.z * inv * gg.z;
            ov.w = av.w * inv * gg.w;
            *(float4*)&smem[t * 36 + (c4 << 2)] = ov;
        }
        __syncthreads();
        #pragma unroll
        for (int it = 0; it < 8; ++it) {   // coalesced store of gated half
            int flat = t + (it << 7);
            int row = flat >> 3, c4 = flat & 7;
            *(float4*)&gated[base + (size_t)((rr << 7) + row) * CCH + (c4 << 2)] =
                *(const float4*)&smem[row * 36 + (c4 << 2)];
        }
    }
}

// ---------------- output projection: [65536,128] @ [128,128] + bo ----------------
__global__ __launch_bounds__(256) void out_gemm_kernel(
    const float* __restrict__ A, const float* __restrict__ wo,
    const float* __restrict__ bo, float* __restrict__ out)
{
    __shared__ float as[64][68];
    __shared__ float bs[64][64];
    const int t = threadIdx.x;
    const int r0 = blockIdx.x << 6;
    const int c0 = blockIdx.y << 6;
    const int tr = t >> 4, tc = t & 15;
    float acc[4][4];
    #pragma unroll
    for (int u = 0; u < 4; ++u)
        #pragma unroll
        for (int w = 0; w < 4; ++w) acc[u][w] = 0.0f;

    for (int k0 = 0; k0 < CCH; k0 += 64) {
        __syncthreads();
        #pragma unroll
        for (int it = 0; it < 4; ++it) {
            int flat = t + (it << 8);
            int row = flat >> 4, q4i = flat & 15;
            *(float4*)&as[row][q4i << 2] =
                *(const float4*)&A[(size_t)(r0 + row) * CCH + k0 + (q4i << 2)];
            *(float4*)&bs[row][q4i << 2] =
                *(const float4*)&wo[(size_t)(k0 + row) * CCH + c0 + (q4i << 2)];
        }
        __syncthreads();
        #pragma unroll 8
        for (int k = 0; k < 64; ++k) {
            float4 b4 = *(const float4*)&bs[k][tc << 2];
            #pragma unroll
            for (int u = 0; u < 4; ++u) {
                float av = as[(tr << 2) + u][k];
                acc[u][0] = fmaf(av, b4.x, acc[u][0]);
                acc[u][1] = fmaf(av, b4.y, acc[u][1]);
                acc[u][2] = fmaf(av, b4.z, acc[u][2]);
                acc[u][3] = fmaf(av, b4.w, acc[u][3]);
            }
        }
    }
    #pragma unroll
    for (int u = 0; u < 4; ++u) {
        int row = r0 + (tr << 2) + u;
        int c = c0 + (tc << 2);
        float4 ov = make_float4(acc[u][0] + bo[c],     acc[u][1] + bo[c + 1],
                                acc[u][2] + bo[c + 2], acc[u][3] + bo[c + 3]);
        *(float4*)&out[(size_t)row * CCH + c] = ov;
    }
}

extern "C" void kernel_launch(void* const* d_in, const int* in_sizes, int n_in,
                              void* d_out, int out_size, void* d_ws, size_t ws_size,
                              hipStream_t stream)
{
    const float* act  = (const float*)d_in[0];
    const float* mask = (const float*)d_in[1];
    const float* ln_g = (const float*)d_in[2];
    const float* ln_b = (const float*)d_in[3];
    const float* wq   = (const float*)d_in[4];
    const float* wk   = (const float*)d_in[5];
    const float* wv   = (const float*)d_in[6];
    const float* w2d  = (const float*)d_in[7];
    const float* wg   = (const float*)d_in[8];
    const float* bg   = (const float*)d_in[9];
    const float* wo   = (const float*)d_in[10];
    const float* bo   = (const float*)d_in[11];
    float* out = (float*)d_out;
    float* ws  = (float*)d_ws;

    // workspace layout (floats): a | q | k | v | g | nbT  (~161 MB total)
    const size_t SZ = (size_t)NROWS * CCH;
    float* a    = ws;
    float* qb   = ws + SZ;
    float* kb   = ws + 2 * SZ;
    float* vb   = ws + 3 * SZ;
    float* gb   = ws + 4 * SZ;
    float* nbT  = ws + 5 * SZ;
    float* gated = a;   // a is dead after proj_gemm; reuse for gated output

    ln_nb_kernel<<<NROWS / 4, 256, 0, stream>>>(act, ln_g, ln_b, w2d, a, nbT);
    proj_gemm_kernel<<<dim3(NROWS / 64, 8), 256, 0, stream>>>(
        a, wq, wk, wv, wg, bg, qb, kb, vb, gb);
    attn_kernel<<<NRES * 4, 128, 0, stream>>>(qb, kb, vb, gb, mask, nbT, gated);
    out_gemm_kernel<<<dim3(NROWS / 64, 2), 256, 0, stream>>>(gated, wo, bo, out);
}

// Round 2
// 447.787 us; speedup vs baseline: 1.4081x; 1.4081x over previous
//
#include <hip/hip_runtime.h>
#include <math.h>

// TriangleAttentionStartingNode: B=1, N=256, C=128, H=4, AC=32, fp32 in/out.
// R1: attn rewritten with split-bf16 (hi+lo) MFMA 16x16x32 — 3 MFMAs per
// logical fp32 product gives ~2^-17 relative error (threshold 1.83e-4, fp32
// baseline was 3.05e-5). ln/proj/out kernels unchanged except nb layout.

#define NRES 256
#define CCH  128
#define NROWS (NRES * NRES)          // 65536
#define FACTOR 0.17677669529663687f  // 1/sqrt(32)

typedef __attribute__((ext_vector_type(8))) __bf16 bf16x8;
typedef __attribute__((ext_vector_type(4))) float f32x4;

__device__ __forceinline__ f32x4 mfma16(bf16x8 a, bf16x8 b, f32x4 c) {
    return __builtin_amdgcn_mfma_f32_16x16x32_bf16(a, b, c, 0, 0, 0);
}

__device__ __forceinline__ void cvt8(const float* t, bf16x8& hi, bf16x8& lo) {
    #pragma unroll
    for (int i = 0; i < 8; ++i) {
        __bf16 h = (__bf16)t[i];
        hi[i] = h;
        lo[i] = (__bf16)(t[i] - (float)h);
    }
}

__device__ __forceinline__ void load_frag_hilo(const float* __restrict__ p,
                                               bf16x8& hi, bf16x8& lo) {
    float4 f0 = *(const float4*)p;
    float4 f1 = *(const float4*)(p + 4);
    float t[8] = {f0.x, f0.y, f0.z, f0.w, f1.x, f1.y, f1.z, f1.w};
    cvt8(t, hi, lo);
}

// ---------------- LayerNorm + pair-bias nb (fused) ----------------
// One wave per row of 128 ch. nb written in NATURAL layout nbN[h][i][j]
// (i = first res index of act row), L2-resident for attn.
__global__ __launch_bounds__(256) void ln_nb_kernel(
    const float* __restrict__ act, const float* __restrict__ ln_g,
    const float* __restrict__ ln_b, const float* __restrict__ w2d,
    float* __restrict__ a_out, float* __restrict__ nbN)
{
    const int wid = threadIdx.x >> 6;
    const int lane = threadIdx.x & 63;
    const int row = (blockIdx.x << 2) | wid;
    const float* __restrict__ x = act + (size_t)row * CCH;
    const int c0 = lane << 1;
    float x0 = x[c0], x1 = x[c0 + 1];
    float s = x0 + x1;
    float sq = fmaf(x0, x0, x1 * x1);
    #pragma unroll
    for (int o = 32; o > 0; o >>= 1) {
        s  += __shfl_xor(s, o, 64);
        sq += __shfl_xor(sq, o, 64);
    }
    float mu  = s * (1.0f / CCH);
    float var = fmaf(sq, 1.0f / CCH, -mu * mu);
    float rs  = rsqrtf(var + 1e-5f);
    float a0 = fmaf((x0 - mu) * rs, ln_g[c0],     ln_b[c0]);
    float a1 = fmaf((x1 - mu) * rs, ln_g[c0 + 1], ln_b[c0 + 1]);
    a_out[(size_t)row * CCH + c0]     = a0;
    a_out[(size_t)row * CCH + c0 + 1] = a1;
    float nb0 = fmaf(a0, w2d[c0 * 4 + 0], a1 * w2d[(c0 + 1) * 4 + 0]);
    float nb1 = fmaf(a0, w2d[c0 * 4 + 1], a1 * w2d[(c0 + 1) * 4 + 1]);
    float nb2 = fmaf(a0, w2d[c0 * 4 + 2], a1 * w2d[(c0 + 1) * 4 + 2]);
    float nb3 = fmaf(a0, w2d[c0 * 4 + 3], a1 * w2d[(c0 + 1) * 4 + 3]);
    #pragma unroll
    for (int o = 32; o > 0; o >>= 1) {
        nb0 += __shfl_xor(nb0, o, 64);
        nb1 += __shfl_xor(nb1, o, 64);
        nb2 += __shfl_xor(nb2, o, 64);
        nb3 += __shfl_xor(nb3, o, 64);
    }
    if (lane == 0) {
        nbN[row]             = nb0;   // natural [h][i][j], row = i*256+j
        nbN[NROWS + row]     = nb1;
        nbN[2 * NROWS + row] = nb2;
        nbN[3 * NROWS + row] = nb3;
    }
}

// ---------------- projection GEMM: [65536,128] @ [128,128] x4 ----------------
__global__ __launch_bounds__(256) void proj_gemm_kernel(
    const float* __restrict__ A,
    const float* __restrict__ wq, const float* __restrict__ wk,
    const float* __restrict__ wv, const float* __restrict__ wg,
    const float* __restrict__ bg,
    float* __restrict__ qb, float* __restrict__ kb,
    float* __restrict__ vb, float* __restrict__ gb)
{
    __shared__ float as[64][68];
    __shared__ float bs[64][64];
    const int t = threadIdx.x;
    const int rb = blockIdx.x;
    const int cb = blockIdx.y;
    const int tensor = cb >> 1;
    const int c0 = (cb & 1) << 6;
    const float* __restrict__ W =
        (tensor == 0) ? wq : (tensor == 1) ? wk : (tensor == 2) ? wv : wg;
    const int tr = t >> 4, tc = t & 15;
    const int r0 = rb << 6;
    float acc[4][4];
    #pragma unroll
    for (int u = 0; u < 4; ++u)
        #pragma unroll
        for (int w = 0; w < 4; ++w) acc[u][w] = 0.0f;

    for (int k0 = 0; k0 < CCH; k0 += 64) {
        __syncthreads();
        #pragma unroll
        for (int it = 0; it < 4; ++it) {
            int flat = t + (it << 8);
            int row = flat >> 4, q4i = flat & 15;
            *(float4*)&as[row][q4i << 2] =
                *(const float4*)&A[(size_t)(r0 + row) * CCH + k0 + (q4i << 2)];
            *(float4*)&bs[row][q4i << 2] =
                *(const float4*)&W[(size_t)(k0 + row) * CCH + c0 + (q4i << 2)];
        }
        __syncthreads();
        #pragma unroll 8
        for (int k = 0; k < 64; ++k) {
            float4 b4 = *(const float4*)&bs[k][tc << 2];
            #pragma unroll
            for (int u = 0; u < 4; ++u) {
                float av = as[(tr << 2) + u][k];
                acc[u][0] = fmaf(av, b4.x, acc[u][0]);
                acc[u][1] = fmaf(av, b4.y, acc[u][1]);
                acc[u][2] = fmaf(av, b4.z, acc[u][2]);
                acc[u][3] = fmaf(av, b4.w, acc[u][3]);
            }
        }
    }
    float* __restrict__ OUT =
        (tensor == 0) ? qb : (tensor == 1) ? kb : (tensor == 2) ? vb : gb;
    #pragma unroll
    for (int u = 0; u < 4; ++u) {
        int row = r0 + (tr << 2) + u;
        int c = c0 + (tc << 2);
        float o0 = acc[u][0], o1 = acc[u][1], o2 = acc[u][2], o3 = acc[u][3];
        if (tensor == 0) {
            o0 *= FACTOR; o1 *= FACTOR; o2 *= FACTOR; o3 *= FACTOR;
        } else if (tensor == 3) {
            o0 = 1.0f / (1.0f + __expf(-(o0 + bg[c])));
            o1 = 1.0f / (1.0f + __expf(-(o1 + bg[c + 1])));
            o2 = 1.0f / (1.0f + __expf(-(o2 + bg[c + 2])));
            o3 = 1.0f / (1.0f + __expf(-(o3 + bg[c + 3])));
        }
        *(float4*)&OUT[(size_t)row * CCH + c] = make_float4(o0, o1, o2, o3);
    }
}

// ---------------- attention: split-bf16 MFMA flash ----------------
// Block = (m,h), 256 thr = 4 waves; wave w owns q-rows [64w,64w+64) as 4
// strips of 16. Q/K/V frags loaded straight from global in MFMA layout
// (A: [m=lane&15][k=quad*8+j]; B: [k=quad*8+j][n=lane&15] for V,
//  B^T-rows for K). P goes C-layout -> per-wave LDS (stride 40 bf16,
// 16B-aligned, <=2-way banks) -> A-layout frags. 3 MFMAs per split product.
__global__ __launch_bounds__(256) void attn_kernel(
    const float* __restrict__ qb, const float* __restrict__ kb,
    const float* __restrict__ vb, const float* __restrict__ gb,
    const float* __restrict__ mask, const float* __restrict__ nbN,
    float* __restrict__ gated)
{
    __shared__ float biasrow[256];
    __shared__ __bf16 pbuf[4][2][64 * 40];   // [wave][hi/lo][row*40+col]
    const int t = threadIdx.x;
    const int w = t >> 6, lane = t & 63;
    const int quad = lane >> 4, l15 = lane & 15;
    const int mrow = blockIdx.x >> 2, h = blockIdx.x & 3;
    const size_t base = (size_t)mrow * NRES * CCH + h * 32;

    biasrow[t] = 1e9f * (mask[mrow * NRES + t] - 1.0f);
    __syncthreads();

    // Q fragments (A layout), FACTOR already applied in proj
    bf16x8 qhi[4], qlo[4];
    #pragma unroll
    for (int s = 0; s < 4; ++s) {
        int row = w * 64 + s * 16 + l15;
        load_frag_hilo(qb + base + (size_t)row * CCH + quad * 8, qhi[s], qlo[s]);
    }

    f32x4 Oa[4][2];
    f32x4 mst[4], lps[4];
    #pragma unroll
    for (int s = 0; s < 4; ++s) {
        Oa[s][0] = (f32x4){0.f, 0.f, 0.f, 0.f};
        Oa[s][1] = (f32x4){0.f, 0.f, 0.f, 0.f};
        mst[s] = (f32x4){-1e30f, -1e30f, -1e30f, -1e30f};
        lps[s] = (f32x4){0.f, 0.f, 0.f, 0.f};
    }
    const float* __restrict__ nbp = nbN + (size_t)h * NROWS;
    __bf16* const ph = &pbuf[w][0][0];
    __bf16* const pl = &pbuf[w][1][0];

    for (int jb = 0; jb < NRES; jb += 32) {
        // K fragments (B^T rows = K rows)
        bf16x8 khi[2], klo[2];
        #pragma unroll
        for (int ct = 0; ct < 2; ++ct)
            load_frag_hilo(kb + base + (size_t)(jb + ct * 16 + l15) * CCH + quad * 8,
                           khi[ct], klo[ct]);
        // V fragments (B layout: k=j rows, n=channel)
        bf16x8 vhi[2], vlo[2];
        #pragma unroll
        for (int vt = 0; vt < 2; ++vt) {
            float tmp[8];
            #pragma unroll
            for (int jj = 0; jj < 8; ++jj)
                tmp[jj] = vb[base + (size_t)(jb + quad * 8 + jj) * CCH + vt * 16 + l15];
            cvt8(tmp, vhi[vt], vlo[vt]);
        }
        const float br0 = biasrow[jb + l15];
        const float br1 = biasrow[jb + 16 + l15];

        #pragma unroll
        for (int s = 0; s < 4; ++s) {
            f32x4 c0 = (f32x4){0.f, 0.f, 0.f, 0.f};
            f32x4 c1 = (f32x4){0.f, 0.f, 0.f, 0.f};
            c0 = mfma16(qhi[s], khi[0], c0);
            c0 = mfma16(qhi[s], klo[0], c0);
            c0 = mfma16(qlo[s], khi[0], c0);
            c1 = mfma16(qhi[s], khi[1], c1);
            c1 = mfma16(qhi[s], klo[1], c1);
            c1 = mfma16(qlo[s], khi[1], c1);

            const int rowb = w * 64 + s * 16 + quad * 4;
            #pragma unroll
            for (int r = 0; r < 4; ++r) {
                size_t nbo = (size_t)(rowb + r) * NRES + jb;
                c0[r] += br0 + nbp[nbo + l15];
                c1[r] += br1 + nbp[nbo + 16 + l15];
            }
            // online softmax (rows live across 16 lanes of same quad)
            f32x4 cm;
            #pragma unroll
            for (int r = 0; r < 4; ++r) cm[r] = fmaxf(c0[r], c1[r]);
            #pragma unroll
            for (int o = 1; o <= 8; o <<= 1)
                #pragma unroll
                for (int r = 0; r < 4; ++r)
                    cm[r] = fmaxf(cm[r], __shfl_xor(cm[r], o, 64));
            #pragma unroll
            for (int r = 0; r < 4; ++r) {
                float mn = fmaxf(mst[s][r], cm[r]);
                float alpha = __expf(mst[s][r] - mn);
                mst[s][r] = mn;
                float p0 = __expf(c0[r] - mn);
                float p1 = __expf(c1[r] - mn);
                lps[s][r] = lps[s][r] * alpha + p0 + p1;
                Oa[s][0][r] *= alpha;
                Oa[s][1][r] *= alpha;
                c0[r] = p0;
                c1[r] = p1;
            }
            // P -> per-wave LDS (hi/lo), stride 40 bf16
            #pragma unroll
            for (int r = 0; r < 4; ++r) {
                int lr = (s * 16 + quad * 4 + r) * 40;
                __bf16 h0 = (__bf16)c0[r];
                __bf16 h1 = (__bf16)c1[r];
                ph[lr + l15]      = h0;
                ph[lr + 16 + l15] = h1;
                pl[lr + l15]      = (__bf16)(c0[r] - (float)h0);
                pl[lr + 16 + l15] = (__bf16)(c1[r] - (float)h1);
            }
        }
        // PV: read P as A-layout frags (per-wave buffer, in-wave lgkmcnt dep)
        #pragma unroll
        for (int s = 0; s < 4; ++s) {
            int off = (s * 16 + l15) * 40 + quad * 8;
            bf16x8 phf = *(const bf16x8*)(ph + off);
            bf16x8 plf = *(const bf16x8*)(pl + off);
            #pragma unroll
            for (int vt = 0; vt < 2; ++vt) {
                Oa[s][vt] = mfma16(phf, vhi[vt], Oa[s][vt]);
                Oa[s][vt] = mfma16(phf, vlo[vt], Oa[s][vt]);
                Oa[s][vt] = mfma16(plf, vhi[vt], Oa[s][vt]);
            }
        }
    }

    // final row-sum reduce, gate, store
    #pragma unroll
    for (int s = 0; s < 4; ++s)
        #pragma unroll
        for (int o = 1; o <= 8; o <<= 1)
            #pragma unroll
            for (int r = 0; r < 4; ++r)
                lps[s][r] += __shfl_xor(lps[s][r], o, 64);

    #pragma unroll
    for (int s = 0; s < 4; ++s) {
        const int rowb = w * 64 + s * 16 + quad * 4;
        #pragma unroll
        for (int r = 0; r < 4; ++r) {
            float inv = 1.0f / lps[s][r];
            size_t o = base + (size_t)(rowb + r) * CCH + l15;
            gated[o]      = Oa[s][0][r] * inv * gb[o];
            gated[o + 16] = Oa[s][1][r] * inv * gb[o + 16];
        }
    }
}

// ---------------- output projection: [65536,128] @ [128,128] + bo ----------------
__global__ __launch_bounds__(256) void out_gemm_kernel(
    const float* __restrict__ A, const float* __restrict__ wo,
    const float* __restrict__ bo, float* __restrict__ out)
{
    __shared__ float as[64][68];
    __shared__ float bs[64][64];
    const int t = threadIdx.x;
    const int r0 = blockIdx.x << 6;
    const int c0 = blockIdx.y << 6;
    const int tr = t >> 4, tc = t & 15;
    float acc[4][4];
    #pragma unroll
    for (int u = 0; u < 4; ++u)
        #pragma unroll
        for (int w = 0; w < 4; ++w) acc[u][w] = 0.0f;

    for (int k0 = 0; k0 < CCH; k0 += 64) {
        __syncthreads();
        #pragma unroll
        for (int it = 0; it < 4; ++it) {
            int flat = t + (it << 8);
            int row = flat >> 4, q4i = flat & 15;
            *(float4*)&as[row][q4i << 2] =
                *(const float4*)&A[(size_t)(r0 + row) * CCH + k0 + (q4i << 2)];
            *(float4*)&bs[row][q4i << 2] =
                *(const float4*)&wo[(size_t)(k0 + row) * CCH + c0 + (q4i << 2)];
        }
        __syncthreads();
        #pragma unroll 8
        for (int k = 0; k < 64; ++k) {
            float4 b4 = *(const float4*)&bs[k][tc << 2];
            #pragma unroll
            for (int u = 0; u < 4; ++u) {
                float av = as[(tr << 2) + u][k];
                acc[u][0] = fmaf(av, b4.x, acc[u][0]);
                acc[u][1] = fmaf(av, b4.y, acc[u][1]);
                acc[u][2] = fmaf(av, b4.z, acc[u][2]);
                acc[u][3] = fmaf(av, b4.w, acc[u][3]);
            }
        }
    }
    #pragma unroll
    for (int u = 0; u < 4; ++u) {
        int row = r0 + (tr << 2) + u;
        int c = c0 + (tc << 2);
        float4 ov = make_float4(acc[u][0] + bo[c],     acc[u][1] + bo[c + 1],
                                acc[u][2] + bo[c + 2], acc[u][3] + bo[c + 3]);
        *(float4*)&out[(size_t)row * CCH + c] = ov;
    }
}

extern "C" void kernel_launch(void* const* d_in, const int* in_sizes, int n_in,
                              void* d_out, int out_size, void* d_ws, size_t ws_size,
                              hipStream_t stream)
{
    const float* act  = (const float*)d_in[0];
    const float* mask = (const float*)d_in[1];
    const float* ln_g = (const float*)d_in[2];
    const float* ln_b = (const float*)d_in[3];
    const float* wq   = (const float*)d_in[4];
    const float* wk   = (const float*)d_in[5];
    const float* wv   = (const float*)d_in[6];
    const float* w2d  = (const float*)d_in[7];
    const float* wg   = (const float*)d_in[8];
    const float* bg   = (const float*)d_in[9];
    const float* wo   = (const float*)d_in[10];
    const float* bo   = (const float*)d_in[11];
    float* out = (float*)d_out;
    float* ws  = (float*)d_ws;

    const size_t SZ = (size_t)NROWS * CCH;
    float* a    = ws;
    float* qb   = ws + SZ;
    float* kb   = ws + 2 * SZ;
    float* vb   = ws + 3 * SZ;
    float* gb   = ws + 4 * SZ;
    float* nbN  = ws + 5 * SZ;
    float* gated = a;   // a dead after proj_gemm; reuse

    ln_nb_kernel<<<NROWS / 4, 256, 0, stream>>>(act, ln_g, ln_b, w2d, a, nbN);
    proj_gemm_kernel<<<dim3(NROWS / 64, 8), 256, 0, stream>>>(
        a, wq, wk, wv, wg, bg, qb, kb, vb, gb);
    attn_kernel<<<NRES * 4, 256, 0, stream>>>(qb, kb, vb, gb, mask, nbN, gated);
    out_gemm_kernel<<<dim3(NROWS / 64, 2), 256, 0, stream>>>(gated, wo, bo, out);
}

// Round 3
// 343.018 us; speedup vs baseline: 1.8382x; 1.3054x over previous
//
#include <hip/hip_runtime.h>
#include <math.h>

// TriangleAttentionStartingNode: B=1, N=256, C=128, H=4, AC=32, fp32 in/out.
// R2: everything matmul-shaped on split-bf16 (hi+lo) MFMA 16x16x32.
//  - prep: pack wq*FACTOR,wk,wv,wg,wo into B-frag layout bf16 hi/lo
//  - ln: LayerNorm -> a as bf16 hi/lo + pair-bias nb (natural [h][i][j])
//  - proj: a @ W for q,k,v (bf16 hi/lo out), g (sigmoid, fp32 out)
//  - attn: S^T = K*Q^T (C-layout gives 4 consecutive j per lane -> float4
//    bias loads, cheap softmax), fixed-shift softmax (shift-invariant),
//    PV as O^T = V^T*P^T with V^T staged in LDS; gated out bf16 hi/lo
//  - out: gated @ wo + bo -> fp32

#define NRES 256
#define CCH  128
#define NROWS (NRES * NRES)          // 65536
#define FACTOR 0.17677669529663687f  // 1/sqrt(32)

typedef __attribute__((ext_vector_type(8))) __bf16 bf16x8;
typedef __attribute__((ext_vector_type(4))) float f32x4;

__device__ __forceinline__ f32x4 mfma16(bf16x8 a, bf16x8 b, f32x4 c) {
    return __builtin_amdgcn_mfma_f32_16x16x32_bf16(a, b, c, 0, 0, 0);
}

union PK4 { __bf16 b[4]; uint2 u2; };
union PK2 { __bf16 b[2]; unsigned int u; };

__device__ __forceinline__ void hilo(float x, __bf16& h, __bf16& l) {
    h = (__bf16)x;
    l = (__bf16)(x - (float)h);
}

// ---------------- weight prep: pack into B-frag layout ----------------
// frag slot gid = wid*2048 + nstrip*256 + kfrag*64 + lane; elem e:
// value = W[kfrag*32 + quad*8 + e][nstrip*16 + l15] * scale
__global__ __launch_bounds__(256) void prep_kernel(
    const float* __restrict__ wq, const float* __restrict__ wk,
    const float* __restrict__ wv, const float* __restrict__ wg,
    const float* __restrict__ wo,
    __bf16* __restrict__ wph, __bf16* __restrict__ wpl)
{
    const int gid = blockIdx.x * 256 + threadIdx.x;   // 0..10239
    const int wid = gid >> 11;
    const int rem = gid & 2047;
    const int nstrip = rem >> 8;
    const int kf = (rem >> 6) & 3;
    const int lane = rem & 63;
    const int l15 = lane & 15, quad = lane >> 4;
    const float* W = (wid == 0) ? wq : (wid == 1) ? wk :
                     (wid == 2) ? wv : (wid == 3) ? wg : wo;
    const float scale = (wid == 0) ? FACTOR : 1.0f;
    bf16x8 hb, lb;
    #pragma unroll
    for (int e = 0; e < 8; ++e) {
        int k = kf * 32 + quad * 8 + e;
        int n = nstrip * 16 + l15;
        float v = W[k * CCH + n] * scale;
        __bf16 h, l; hilo(v, h, l);
        hb[e] = h; lb[e] = l;
    }
    *(bf16x8*)&wph[(size_t)gid * 8] = hb;
    *(bf16x8*)&wpl[(size_t)gid * 8] = lb;
}

// ---------------- LayerNorm + pair-bias nb ----------------
__global__ __launch_bounds__(256) void ln_nb_kernel(
    const float* __restrict__ act, const float* __restrict__ ln_g,
    const float* __restrict__ ln_b, const float* __restrict__ w2d,
    __bf16* __restrict__ ah, __bf16* __restrict__ al,
    float* __restrict__ nbN)
{
    const int wid = threadIdx.x >> 6;
    const int lane = threadIdx.x & 63;
    const int row = (blockIdx.x << 2) | wid;
    const float* __restrict__ x = act + (size_t)row * CCH;
    const int c0 = lane << 1;
    float2 xv = *(const float2*)&x[c0];
    float x0 = xv.x, x1 = xv.y;
    float s = x0 + x1;
    float sq = fmaf(x0, x0, x1 * x1);
    #pragma unroll
    for (int o = 32; o > 0; o >>= 1) {
        s  += __shfl_xor(s, o, 64);
        sq += __shfl_xor(sq, o, 64);
    }
    float mu  = s * (1.0f / CCH);
    float var = fmaf(sq, 1.0f / CCH, -mu * mu);
    float rs  = rsqrtf(var + 1e-5f);
    float a0 = fmaf((x0 - mu) * rs, ln_g[c0],     ln_b[c0]);
    float a1 = fmaf((x1 - mu) * rs, ln_g[c0 + 1], ln_b[c0 + 1]);
    __bf16 h0, l0, h1, l1;
    hilo(a0, h0, l0); hilo(a1, h1, l1);
    PK2 ph; ph.b[0] = h0; ph.b[1] = h1;
    PK2 pl; pl.b[0] = l0; pl.b[1] = l1;
    *(unsigned int*)&ah[(size_t)row * CCH + c0] = ph.u;
    *(unsigned int*)&al[(size_t)row * CCH + c0] = pl.u;
    float nb0 = fmaf(a0, w2d[c0 * 4 + 0], a1 * w2d[(c0 + 1) * 4 + 0]);
    float nb1 = fmaf(a0, w2d[c0 * 4 + 1], a1 * w2d[(c0 + 1) * 4 + 1]);
    float nb2 = fmaf(a0, w2d[c0 * 4 + 2], a1 * w2d[(c0 + 1) * 4 + 2]);
    float nb3 = fmaf(a0, w2d[c0 * 4 + 3], a1 * w2d[(c0 + 1) * 4 + 3]);
    #pragma unroll
    for (int o = 32; o > 0; o >>= 1) {
        nb0 += __shfl_xor(nb0, o, 64);
        nb1 += __shfl_xor(nb1, o, 64);
        nb2 += __shfl_xor(nb2, o, 64);
        nb3 += __shfl_xor(nb3, o, 64);
    }
    if (lane == 0) {
        nbN[row]             = nb0;   // [h][i][j], row = i*256+j
        nbN[NROWS + row]     = nb1;
        nbN[2 * NROWS + row] = nb2;
        nbN[3 * NROWS + row] = nb3;
    }
}

// ---------------- projection GEMM (MFMA): [65536,128]@[128,128] x4 ----------------
// grid (256 rowblocks, 4 tensors); block 256 = 4 waves x 64 rows.
__global__ __launch_bounds__(256) void proj_kernel(
    const __bf16* __restrict__ ah, const __bf16* __restrict__ al,
    const __bf16* __restrict__ wph, const __bf16* __restrict__ wpl,
    const float* __restrict__ bg,
    __bf16* __restrict__ qh, __bf16* __restrict__ ql,
    __bf16* __restrict__ kh, __bf16* __restrict__ kl,
    __bf16* __restrict__ vh, __bf16* __restrict__ vl,
    float* __restrict__ gfp)
{
    __shared__ float eps[4][16][132];
    const int t = threadIdx.x, w = t >> 6, lane = t & 63;
    const int l15 = lane & 15, quad = lane >> 4;
    const int tensor = blockIdx.y;
    const int r0 = blockIdx.x * 256 + w * 64;
    const __bf16* __restrict__ Bh = wph + (size_t)tensor * 16384;
    const __bf16* __restrict__ Bl = wpl + (size_t)tensor * 16384;

    f32x4 acc[4][8];
    #pragma unroll
    for (int s = 0; s < 4; ++s)
        #pragma unroll
        for (int n = 0; n < 8; ++n) acc[s][n] = (f32x4){0.f, 0.f, 0.f, 0.f};

    #pragma unroll
    for (int kf = 0; kf < 4; ++kf) {
        bf16x8 Ahf[4], Alf[4];
        #pragma unroll
        for (int s = 0; s < 4; ++s) {
            size_t idx = (size_t)(r0 + s * 16 + l15) * CCH + kf * 32 + quad * 8;
            Ahf[s] = *(const bf16x8*)&ah[idx];
            Alf[s] = *(const bf16x8*)&al[idx];
        }
        #pragma unroll
        for (int n = 0; n < 8; ++n) {
            size_t boff = (size_t)((n * 4 + kf) * 64 + lane) * 8;
            bf16x8 bh = *(const bf16x8*)&Bh[boff];
            bf16x8 bl = *(const bf16x8*)&Bl[boff];
            #pragma unroll
            for (int s = 0; s < 4; ++s) {
                acc[s][n] = mfma16(Ahf[s], bh, acc[s][n]);
                acc[s][n] = mfma16(Ahf[s], bl, acc[s][n]);
                acc[s][n] = mfma16(Alf[s], bh, acc[s][n]);
            }
        }
    }

    __bf16 *oh = qh, *ol = ql;
    if (tensor == 1) { oh = kh; ol = kl; }
    else if (tensor == 2) { oh = vh; ol = vl; }
    const int erow = lane >> 2;
    const int ecg0 = lane & 3;

    #pragma unroll 1
    for (int s = 0; s < 4; ++s) {
        #pragma unroll
        for (int n = 0; n < 8; ++n)
            #pragma unroll
            for (int r = 0; r < 4; ++r)
                eps[w][quad * 4 + r][n * 16 + l15] = acc[s][n][r];
        #pragma unroll
        for (int it = 0; it < 8; ++it) {
            int cg = ecg0 + it * 4;                 // 0..31
            float4 v4 = *(const float4*)&eps[w][erow][cg * 4];
            size_t grow = (size_t)(r0 + s * 16 + erow);
            int gcol = cg * 4;
            if (tensor == 3) {
                float4 b4 = *(const float4*)&bg[gcol];
                float4 r4;
                r4.x = 1.0f / (1.0f + __expf(-(v4.x + b4.x)));
                r4.y = 1.0f / (1.0f + __expf(-(v4.y + b4.y)));
                r4.z = 1.0f / (1.0f + __expf(-(v4.z + b4.z)));
                r4.w = 1.0f / (1.0f + __expf(-(v4.w + b4.w)));
                *(float4*)&gfp[grow * CCH + gcol] = r4;
            } else {
                PK4 hh, ll;
                hilo(v4.x, hh.b[0], ll.b[0]);
                hilo(v4.y, hh.b[1], ll.b[1]);
                hilo(v4.z, hh.b[2], ll.b[2]);
                hilo(v4.w, hh.b[3], ll.b[3]);
                *(uint2*)&oh[grow * CCH + gcol] = hh.u2;
                *(uint2*)&ol[grow * CCH + gcol] = ll.u2;
            }
        }
    }
}

// ---------------- attention: S^T path, fixed-shift softmax ----------------
__global__ __launch_bounds__(256) void attn_kernel(
    const __bf16* __restrict__ qh, const __bf16* __restrict__ ql,
    const __bf16* __restrict__ kh, const __bf16* __restrict__ kl,
    const __bf16* __restrict__ vh, const __bf16* __restrict__ vl,
    const float* __restrict__ gfp, const float* __restrict__ mask,
    const float* __restrict__ nbN,
    __bf16* __restrict__ gth, __bf16* __restrict__ gtl)
{
    __shared__ __bf16 vth[32][264];
    __shared__ __bf16 vtl[32][264];
    __shared__ __bf16 pb[4][2][16][40];
    __shared__ float biasrow[256];
    const int t = threadIdx.x, w = t >> 6, lane = t & 63;
    const int l15 = lane & 15, quad = lane >> 4;
    const int mrow = blockIdx.x >> 2, h = blockIdx.x & 3;
    const size_t rbase = (size_t)mrow * NRES;
    const int ch0 = h * 32;

    biasrow[t] = 1e9f * (mask[mrow * NRES + t] - 1.0f);

    // V^T staging (hi/lo)
    #pragma unroll
    for (int it = 0; it < 4; ++it) {
        int f = t + it * 256;
        int j = f >> 2, cg = f & 3;
        bf16x8 hv = *(const bf16x8*)&vh[(rbase + j) * CCH + ch0 + cg * 8];
        bf16x8 lv = *(const bf16x8*)&vl[(rbase + j) * CCH + ch0 + cg * 8];
        #pragma unroll
        for (int e = 0; e < 8; ++e) {
            vth[cg * 8 + e][j] = hv[e];
            vtl[cg * 8 + e][j] = lv[e];
        }
    }
    __syncthreads();

    const int i0 = w * 64;
    bf16x8 Qh[4], Ql[4];
    #pragma unroll
    for (int s = 0; s < 4; ++s) {
        size_t idx = (rbase + i0 + s * 16 + l15) * CCH + ch0 + quad * 8;
        Qh[s] = *(const bf16x8*)&qh[idx];
        Ql[s] = *(const bf16x8*)&ql[idx];
    }

    f32x4 O[4][2];
    float ls[4] = {0.f, 0.f, 0.f, 0.f};
    #pragma unroll
    for (int s = 0; s < 4; ++s) {
        O[s][0] = (f32x4){0.f, 0.f, 0.f, 0.f};
        O[s][1] = (f32x4){0.f, 0.f, 0.f, 0.f};
    }
    const float* __restrict__ nbp = nbN + (size_t)h * NROWS;

    for (int jb = 0; jb < NRES; jb += 32) {
        bf16x8 Kh[2], Kl[2];
        #pragma unroll
        for (int js = 0; js < 2; ++js) {
            size_t idx = (rbase + jb + js * 16 + l15) * CCH + ch0 + quad * 8;
            Kh[js] = *(const bf16x8*)&kh[idx];
            Kl[js] = *(const bf16x8*)&kl[idx];
        }
        bf16x8 Vh2[2], Vl2[2];
        #pragma unroll
        for (int c = 0; c < 2; ++c) {
            Vh2[c] = *(const bf16x8*)&vth[c * 16 + l15][jb + quad * 8];
            Vl2[c] = *(const bf16x8*)&vtl[c * 16 + l15][jb + quad * 8];
        }
        #pragma unroll
        for (int s = 0; s < 4; ++s) {
            #pragma unroll
            for (int js = 0; js < 2; ++js) {
                f32x4 S = (f32x4){0.f, 0.f, 0.f, 0.f};
                S = mfma16(Kh[js], Qh[s], S);
                S = mfma16(Kh[js], Ql[s], S);
                S = mfma16(Kl[js], Qh[s], S);
                // element r: j = jb+js*16+quad*4+r, i = i0+s*16+l15
                float4 nb4 = *(const float4*)
                    &nbp[(size_t)(i0 + s * 16 + l15) * NRES + jb + js * 16 + quad * 4];
                float4 mb4 = *(const float4*)&biasrow[jb + js * 16 + quad * 4];
                float p0 = __expf(S[0] + nb4.x + mb4.x - 4.0f);
                float p1 = __expf(S[1] + nb4.y + mb4.y - 4.0f);
                float p2 = __expf(S[2] + nb4.z + mb4.z - 4.0f);
                float p3 = __expf(S[3] + nb4.w + mb4.w - 4.0f);
                ls[s] += (p0 + p1) + (p2 + p3);
                PK4 hh, ll;
                hilo(p0, hh.b[0], ll.b[0]);
                hilo(p1, hh.b[1], ll.b[1]);
                hilo(p2, hh.b[2], ll.b[2]);
                hilo(p3, hh.b[3], ll.b[3]);
                *(uint2*)&pb[w][0][l15][js * 16 + quad * 4] = hh.u2;
                *(uint2*)&pb[w][1][l15][js * 16 + quad * 4] = ll.u2;
            }
            bf16x8 Ph = *(const bf16x8*)&pb[w][0][l15][quad * 8];
            bf16x8 Pl = *(const bf16x8*)&pb[w][1][l15][quad * 8];
            #pragma unroll
            for (int c = 0; c < 2; ++c) {
                O[s][c] = mfma16(Vh2[c], Ph, O[s][c]);
                O[s][c] = mfma16(Vl2[c], Ph, O[s][c]);
                O[s][c] = mfma16(Vh2[c], Pl, O[s][c]);
            }
        }
    }

    #pragma unroll
    for (int s = 0; s < 4; ++s) {
        ls[s] += __shfl_xor(ls[s], 16, 64);
        ls[s] += __shfl_xor(ls[s], 32, 64);
    }

    #pragma unroll
    for (int s = 0; s < 4; ++s) {
        float inv = 1.0f / ls[s];
        size_t grow = rbase + i0 + s * 16 + l15;
        #pragma unroll
        for (int c = 0; c < 2; ++c) {
            size_t gi = grow * CCH + ch0 + c * 16 + quad * 4;
            float4 g4 = *(const float4*)&gfp[gi];
            float o0 = O[s][c][0] * inv * g4.x;
            float o1 = O[s][c][1] * inv * g4.y;
            float o2 = O[s][c][2] * inv * g4.z;
            float o3 = O[s][c][3] * inv * g4.w;
            PK4 hh, ll;
            hilo(o0, hh.b[0], ll.b[0]);
            hilo(o1, hh.b[1], ll.b[1]);
            hilo(o2, hh.b[2], ll.b[2]);
            hilo(o3, hh.b[3], ll.b[3]);
            *(uint2*)&gth[gi] = hh.u2;
            *(uint2*)&gtl[gi] = ll.u2;
        }
    }
}

// ---------------- output GEMM (MFMA): gated @ wo + bo -> fp32 ----------------
__global__ __launch_bounds__(256) void out_kernel(
    const __bf16* __restrict__ gth, const __bf16* __restrict__ gtl,
    const __bf16* __restrict__ wph, const __bf16* __restrict__ wpl,
    const float* __restrict__ bo, float* __restrict__ out)
{
    __shared__ float eps[4][16][132];
    const int t = threadIdx.x, w = t >> 6, lane = t & 63;
    const int l15 = lane & 15, quad = lane >> 4;
    const int r0 = blockIdx.x * 256 + w * 64;
    const __bf16* __restrict__ Bh = wph + (size_t)4 * 16384;
    const __bf16* __restrict__ Bl = wpl + (size_t)4 * 16384;

    f32x4 acc[4][8];
    #pragma unroll
    for (int s = 0; s < 4; ++s)
        #pragma unroll
        for (int n = 0; n < 8; ++n) acc[s][n] = (f32x4){0.f, 0.f, 0.f, 0.f};

    #pragma unroll
    for (int kf = 0; kf < 4; ++kf) {
        bf16x8 Ahf[4], Alf[4];
        #pragma unroll
        for (int s = 0; s < 4; ++s) {
            size_t idx = (size_t)(r0 + s * 16 + l15) * CCH + kf * 32 + quad * 8;
            Ahf[s] = *(const bf16x8*)&gth[idx];
            Alf[s] = *(const bf16x8*)&gtl[idx];
        }
        #pragma unroll
        for (int n = 0; n < 8; ++n) {
            size_t boff = (size_t)((n * 4 + kf) * 64 + lane) * 8;
            bf16x8 bh = *(const bf16x8*)&Bh[boff];
            bf16x8 bl = *(const bf16x8*)&Bl[boff];
            #pragma unroll
            for (int s = 0; s < 4; ++s) {
                acc[s][n] = mfma16(Ahf[s], bh, acc[s][n]);
                acc[s][n] = mfma16(Ahf[s], bl, acc[s][n]);
                acc[s][n] = mfma16(Alf[s], bh, acc[s][n]);
            }
        }
    }

    const int erow = lane >> 2;
    const int ecg0 = lane & 3;
    #pragma unroll 1
    for (int s = 0; s < 4; ++s) {
        #pragma unroll
        for (int n = 0; n < 8; ++n)
            #pragma unroll
            for (int r = 0; r < 4; ++r)
                eps[w][quad * 4 + r][n * 16 + l15] = acc[s][n][r];
        #pragma unroll
        for (int it = 0; it < 8; ++it) {
            int cg = ecg0 + it * 4;
            float4 v4 = *(const float4*)&eps[w][erow][cg * 4];
            float4 b4 = *(const float4*)&bo[cg * 4];
            v4.x += b4.x; v4.y += b4.y; v4.z += b4.z; v4.w += b4.w;
            *(float4*)&out[(size_t)(r0 + s * 16 + erow) * CCH + cg * 4] = v4;
        }
    }
}

extern "C" void kernel_launch(void* const* d_in, const int* in_sizes, int n_in,
                              void* d_out, int out_size, void* d_ws, size_t ws_size,
                              hipStream_t stream)
{
    const float* act  = (const float*)d_in[0];
    const float* mask = (const float*)d_in[1];
    const float* ln_g = (const float*)d_in[2];
    const float* ln_b = (const float*)d_in[3];
    const float* wq   = (const float*)d_in[4];
    const float* wk   = (const float*)d_in[5];
    const float* wv   = (const float*)d_in[6];
    const float* w2d  = (const float*)d_in[7];
    const float* wg   = (const float*)d_in[8];
    const float* bg   = (const float*)d_in[9];
    const float* wo   = (const float*)d_in[10];
    const float* bo   = (const float*)d_in[11];
    float* out = (float*)d_out;

    const size_t SZ = (size_t)NROWS * CCH;   // 8388608 elems
    __bf16* bws = (__bf16*)d_ws;
    __bf16* ah = bws;
    __bf16* al = bws + SZ;
    __bf16* qh = bws + 2 * SZ;
    __bf16* ql = bws + 3 * SZ;
    __bf16* kh = bws + 4 * SZ;
    __bf16* kl = bws + 5 * SZ;
    __bf16* vh = bws + 6 * SZ;
    __bf16* vl = bws + 7 * SZ;
    // gated aliases a (dead after proj)
    __bf16* gth = ah;
    __bf16* gtl = al;
    float* fws = (float*)(bws + 8 * SZ);
    float* gfp = fws;                          // SZ floats
    float* nbN = fws + SZ;                     // 4*NROWS floats
    __bf16* wph = (__bf16*)(nbN + 4 * NROWS);  // 5*16384 bf16
    __bf16* wpl = wph + 5 * 16384;

    prep_kernel<<<40, 256, 0, stream>>>(wq, wk, wv, wg, wo, wph, wpl);
    ln_nb_kernel<<<NROWS / 4, 256, 0, stream>>>(act, ln_g, ln_b, w2d, ah, al, nbN);
    proj_kernel<<<dim3(256, 4), 256, 0, stream>>>(
        ah, al, wph, wpl, bg, qh, ql, kh, kl, vh, vl, gfp);
    attn_kernel<<<NRES * 4, 256, 0, stream>>>(
        qh, ql, kh, kl, vh, vl, gfp, mask, nbN, gth, gtl);
    out_kernel<<<256, 256, 0, stream>>>(gth, gtl, wph, wpl, bo, out);
}

// Round 5
// 333.219 us; speedup vs baseline: 1.8922x; 1.0294x over previous
//
#include <hip/hip_runtime.h>
#include <math.h>

// TriangleAttentionStartingNode: B=1, N=256, C=128, H=4, AC=32, fp32 in/out.
// R4: R3 with the gate-epilogue LDS stride bug fixed (68 -> 132). R3 design:
// single-pass all-4-tensor proj (A read once, LDS-staged contiguous uint4
// stores), nb packed into fragment order (nbP), attn gated output staged
// through LDS for 64B-sector stores.

#define NRES 256
#define CCH  128
#define NROWS (NRES * NRES)          // 65536
#define FACTOR 0.17677669529663687f  // 1/sqrt(32)

typedef __attribute__((ext_vector_type(8))) __bf16 bf16x8;
typedef __attribute__((ext_vector_type(4))) float f32x4;

__device__ __forceinline__ f32x4 mfma16(bf16x8 a, bf16x8 b, f32x4 c) {
    return __builtin_amdgcn_mfma_f32_16x16x32_bf16(a, b, c, 0, 0, 0);
}

union PK4 { __bf16 b[4]; uint2 u2; };
union PK2 { __bf16 b[2]; unsigned int u; };

__device__ __forceinline__ void hilo(float x, __bf16& h, __bf16& l) {
    h = (__bf16)x;
    l = (__bf16)(x - (float)h);
}

// ---------------- weight prep: pack into B-frag layout ----------------
// frag slot gid = wid*2048 + nstrip*256 + kfrag*64 + lane; elem e:
// value = W[kfrag*32 + quad*8 + e][nstrip*16 + l15] * scale
__global__ __launch_bounds__(256) void prep_kernel(
    const float* __restrict__ wq, const float* __restrict__ wk,
    const float* __restrict__ wv, const float* __restrict__ wg,
    const float* __restrict__ wo,
    __bf16* __restrict__ wph, __bf16* __restrict__ wpl)
{
    const int gid = blockIdx.x * 256 + threadIdx.x;   // 0..10239
    const int wid = gid >> 11;
    const int rem = gid & 2047;
    const int nstrip = rem >> 8;
    const int kf = (rem >> 6) & 3;
    const int lane = rem & 63;
    const int l15 = lane & 15, quad = lane >> 4;
    const float* W = (wid == 0) ? wq : (wid == 1) ? wk :
                     (wid == 2) ? wv : (wid == 3) ? wg : wo;
    const float scale = (wid == 0) ? FACTOR : 1.0f;
    bf16x8 hb, lb;
    #pragma unroll
    for (int e = 0; e < 8; ++e) {
        int k = kf * 32 + quad * 8 + e;
        int n = nstrip * 16 + l15;
        float v = W[k * CCH + n] * scale;
        __bf16 h, l; hilo(v, h, l);
        hb[e] = h; lb[e] = l;
    }
    *(bf16x8*)&wph[(size_t)gid * 8] = hb;
    *(bf16x8*)&wpl[(size_t)gid * 8] = lb;
}

// ---------------- LayerNorm + pair-bias nb ----------------
__global__ __launch_bounds__(256) void ln_nb_kernel(
    const float* __restrict__ act, const float* __restrict__ ln_g,
    const float* __restrict__ ln_b, const float* __restrict__ w2d,
    __bf16* __restrict__ ah, __bf16* __restrict__ al,
    float* __restrict__ nbN)
{
    const int wid = threadIdx.x >> 6;
    const int lane = threadIdx.x & 63;
    const int row = (blockIdx.x << 2) | wid;
    const float* __restrict__ x = act + (size_t)row * CCH;
    const int c0 = lane << 1;
    float2 xv = *(const float2*)&x[c0];
    float x0 = xv.x, x1 = xv.y;
    float s = x0 + x1;
    float sq = fmaf(x0, x0, x1 * x1);
    #pragma unroll
    for (int o = 32; o > 0; o >>= 1) {
        s  += __shfl_xor(s, o, 64);
        sq += __shfl_xor(sq, o, 64);
    }
    float mu  = s * (1.0f / CCH);
    float var = fmaf(sq, 1.0f / CCH, -mu * mu);
    float rs  = rsqrtf(var + 1e-5f);
    float a0 = fmaf((x0 - mu) * rs, ln_g[c0],     ln_b[c0]);
    float a1 = fmaf((x1 - mu) * rs, ln_g[c0 + 1], ln_b[c0 + 1]);
    __bf16 h0, l0, h1, l1;
    hilo(a0, h0, l0); hilo(a1, h1, l1);
    PK2 ph; ph.b[0] = h0; ph.b[1] = h1;
    PK2 pl; pl.b[0] = l0; pl.b[1] = l1;
    *(unsigned int*)&ah[(size_t)row * CCH + c0] = ph.u;
    *(unsigned int*)&al[(size_t)row * CCH + c0] = pl.u;
    float nb0 = fmaf(a0, w2d[c0 * 4 + 0], a1 * w2d[(c0 + 1) * 4 + 0]);
    float nb1 = fmaf(a0, w2d[c0 * 4 + 1], a1 * w2d[(c0 + 1) * 4 + 1]);
    float nb2 = fmaf(a0, w2d[c0 * 4 + 2], a1 * w2d[(c0 + 1) * 4 + 2]);
    float nb3 = fmaf(a0, w2d[c0 * 4 + 3], a1 * w2d[(c0 + 1) * 4 + 3]);
    #pragma unroll
    for (int o = 32; o > 0; o >>= 1) {
        nb0 += __shfl_xor(nb0, o, 64);
        nb1 += __shfl_xor(nb1, o, 64);
        nb2 += __shfl_xor(nb2, o, 64);
        nb3 += __shfl_xor(nb3, o, 64);
    }
    if (lane == 0) {
        nbN[row]             = nb0;   // [h][i][j], row = i*256+j
        nbN[NROWS + row]     = nb1;
        nbN[2 * NROWS + row] = nb2;
        nbN[3 * NROWS + row] = nb3;
    }
}

// ---------------- nb repack into fragment order ----------------
// float4 slot f: h=f>>14, i16=(f>>10)&15, j16=(f>>6)&15, jq=(f>>4)&3, l=f&15
// nbP[f][r] = nbN[h][i16*16+l][j16*16+jq*4+r]  -> attn wave reads 1KB runs
__global__ __launch_bounds__(256) void nb_pack_kernel(
    const float* __restrict__ nbN, float* __restrict__ nbP)
{
    const int f = blockIdx.x * 256 + threadIdx.x;   // 0..65535
    const int h = f >> 14, i16 = (f >> 10) & 15, j16 = (f >> 6) & 15;
    const int jq = (f >> 4) & 3, l = f & 15;
    const int i = i16 * 16 + l, j = j16 * 16 + jq * 4;
    float4 v = *(const float4*)&nbN[(size_t)h * NROWS + i * NRES + j];
    *(float4*)&nbP[(size_t)f * 4] = v;
}

// ---------------- projection GEMM (MFMA), single pass all 4 tensors --------
// grid 512 x 256thr; wave w owns rows [bx*128 + w*32, +32) as 2 strips of 16.
// A-frags read ONCE; B-frags from L2 feed 6 MFMAs each; epilogue stages
// bf16 hi/lo planes in per-wave LDS, stores contiguous 1KB uint4 runs.
__global__ __launch_bounds__(256) void proj_kernel(
    const __bf16* __restrict__ ah, const __bf16* __restrict__ al,
    const __bf16* __restrict__ wph, const __bf16* __restrict__ wpl,
    const float* __restrict__ bg,
    __bf16* __restrict__ qh, __bf16* __restrict__ ql,
    __bf16* __restrict__ kh, __bf16* __restrict__ kl,
    __bf16* __restrict__ vh, __bf16* __restrict__ vl,
    float* __restrict__ gfp)
{
    __shared__ __align__(16) __bf16 stg[4][2][16 * 136];  // per-wave hi/lo planes
    const int t = threadIdx.x, w = t >> 6, lane = t & 63;
    const int l15 = lane & 15, quad = lane >> 4;
    const int r0 = blockIdx.x * 128 + w * 32;

    bf16x8 Ahf[2][4], Alf[2][4];
    #pragma unroll
    for (int s = 0; s < 2; ++s)
        #pragma unroll
        for (int kf = 0; kf < 4; ++kf) {
            size_t idx = (size_t)(r0 + s * 16 + l15) * CCH + kf * 32 + quad * 8;
            Ahf[s][kf] = *(const bf16x8*)&ah[idx];
            Alf[s][kf] = *(const bf16x8*)&al[idx];
        }

    __bf16* const sth = &stg[w][0][0];
    __bf16* const stl = &stg[w][1][0];

    #pragma unroll 1
    for (int tensor = 0; tensor < 4; ++tensor) {
        f32x4 acc[2][8];
        #pragma unroll
        for (int s = 0; s < 2; ++s)
            #pragma unroll
            for (int n = 0; n < 8; ++n) acc[s][n] = (f32x4){0.f, 0.f, 0.f, 0.f};
        const __bf16* __restrict__ Bh = wph + (size_t)tensor * 16384;
        const __bf16* __restrict__ Bl = wpl + (size_t)tensor * 16384;
        #pragma unroll
        for (int kf = 0; kf < 4; ++kf) {
            #pragma unroll
            for (int n = 0; n < 8; ++n) {
                size_t boff = (size_t)((n * 4 + kf) * 64 + lane) * 8;
                bf16x8 bh = *(const bf16x8*)&Bh[boff];
                bf16x8 bl = *(const bf16x8*)&Bl[boff];
                #pragma unroll
                for (int s = 0; s < 2; ++s) {
                    acc[s][n] = mfma16(Ahf[s][kf], bh, acc[s][n]);
                    acc[s][n] = mfma16(Ahf[s][kf], bl, acc[s][n]);
                    acc[s][n] = mfma16(Alf[s][kf], bh, acc[s][n]);
                }
            }
        }
        if (tensor == 3) {
            // fp32 sigmoid plane: 16 rows x 128 cols, stride 132 (fits in the
            // 8704B per-wave region: 16*132*4 = 8448B). NOTE: stride must
            // exceed max col 127 — this was the R3 bug (had 68).
            float* const stf = (float*)sth;
            #pragma unroll 1
            for (int s = 0; s < 2; ++s) {
                #pragma unroll
                for (int n = 0; n < 8; ++n)
                    #pragma unroll
                    for (int r = 0; r < 4; ++r) {
                        float v = acc[s][n][r] + bg[n * 16 + l15];
                        stf[(quad * 4 + r) * 132 + n * 16 + l15] =
                            1.0f / (1.0f + __expf(-v));
                    }
                #pragma unroll
                for (int i = 0; i < 8; ++i) {
                    int row = i * 2 + (lane >> 5);
                    int c4 = lane & 31;
                    float4 v4 = *(const float4*)&stf[row * 132 + c4 * 4];
                    *(float4*)&gfp[(size_t)(r0 + s * 16 + row) * CCH + c4 * 4] = v4;
                }
            }
        } else {
            __bf16* const oh = (tensor == 0) ? qh : (tensor == 1) ? kh : vh;
            __bf16* const ol = (tensor == 0) ? ql : (tensor == 1) ? kl : vl;
            #pragma unroll 1
            for (int s = 0; s < 2; ++s) {
                #pragma unroll
                for (int n = 0; n < 8; ++n)
                    #pragma unroll
                    for (int r = 0; r < 4; ++r) {
                        __bf16 h, l; hilo(acc[s][n][r], h, l);
                        sth[(quad * 4 + r) * 136 + n * 16 + l15] = h;
                        stl[(quad * 4 + r) * 136 + n * 16 + l15] = l;
                    }
                #pragma unroll
                for (int i = 0; i < 4; ++i) {
                    int row = i * 4 + (lane >> 4);
                    int c8 = lane & 15;
                    uint4 hv = *(const uint4*)&sth[row * 136 + c8 * 8];
                    uint4 lv = *(const uint4*)&stl[row * 136 + c8 * 8];
                    size_t go = (size_t)(r0 + s * 16 + row) * CCH + c8 * 8;
                    *(uint4*)&oh[go] = hv;
                    *(uint4*)&ol[go] = lv;
                }
            }
        }
    }
}

// ---------------- attention: S^T path, fixed-shift softmax ----------------
__global__ __launch_bounds__(256) void attn_kernel(
    const __bf16* __restrict__ qh, const __bf16* __restrict__ ql,
    const __bf16* __restrict__ kh, const __bf16* __restrict__ kl,
    const __bf16* __restrict__ vh, const __bf16* __restrict__ vl,
    const float* __restrict__ gfp, const float* __restrict__ mask,
    const float* __restrict__ nbP,
    __bf16* __restrict__ gth, __bf16* __restrict__ gtl)
{
    __shared__ __align__(16) char smem[45056];
    __bf16* const vth = (__bf16*)smem;               // [32][264]
    __bf16* const vtl = (__bf16*)(smem + 16896);     // [32][264]
    __bf16* const pbb = (__bf16*)(smem + 33792);     // [4][2][16][40]
    float*  const biasrow = (float*)(smem + 44032);  // [256]
    const int t = threadIdx.x, w = t >> 6, lane = t & 63;
    const int l15 = lane & 15, quad = lane >> 4;
    const int mrow = blockIdx.x >> 2, h = blockIdx.x & 3;
    const size_t rbase = (size_t)mrow * NRES;
    const int ch0 = h * 32;

    biasrow[t] = 1e9f * (mask[mrow * NRES + t] - 1.0f);

    // V^T staging (hi/lo)
    #pragma unroll
    for (int it = 0; it < 4; ++it) {
        int f = t + it * 256;
        int j = f >> 2, cg = f & 3;
        bf16x8 hv = *(const bf16x8*)&vh[(rbase + j) * CCH + ch0 + cg * 8];
        bf16x8 lv = *(const bf16x8*)&vl[(rbase + j) * CCH + ch0 + cg * 8];
        #pragma unroll
        for (int e = 0; e < 8; ++e) {
            vth[(cg * 8 + e) * 264 + j] = hv[e];
            vtl[(cg * 8 + e) * 264 + j] = lv[e];
        }
    }
    __syncthreads();

    const int i0 = w * 64;
    bf16x8 Qh[4], Ql[4];
    #pragma unroll
    for (int s = 0; s < 4; ++s) {
        size_t idx = (rbase + i0 + s * 16 + l15) * CCH + ch0 + quad * 8;
        Qh[s] = *(const bf16x8*)&qh[idx];
        Ql[s] = *(const bf16x8*)&ql[idx];
    }

    f32x4 O[4][2];
    float ls[4] = {0.f, 0.f, 0.f, 0.f};
    #pragma unroll
    for (int s = 0; s < 4; ++s) {
        O[s][0] = (f32x4){0.f, 0.f, 0.f, 0.f};
        O[s][1] = (f32x4){0.f, 0.f, 0.f, 0.f};
    }
    __bf16* const ph = pbb + w * 1280;
    __bf16* const pl = ph + 640;

    for (int jb = 0; jb < NRES; jb += 32) {
        bf16x8 Kh[2], Kl[2];
        #pragma unroll
        for (int js = 0; js < 2; ++js) {
            size_t idx = (rbase + jb + js * 16 + l15) * CCH + ch0 + quad * 8;
            Kh[js] = *(const bf16x8*)&kh[idx];
            Kl[js] = *(const bf16x8*)&kl[idx];
        }
        bf16x8 Vh2[2], Vl2[2];
        #pragma unroll
        for (int c = 0; c < 2; ++c) {
            Vh2[c] = *(const bf16x8*)&vth[(c * 16 + l15) * 264 + jb + quad * 8];
            Vl2[c] = *(const bf16x8*)&vtl[(c * 16 + l15) * 264 + jb + quad * 8];
        }
        #pragma unroll
        for (int s = 0; s < 4; ++s) {
            #pragma unroll
            for (int js = 0; js < 2; ++js) {
                f32x4 S = (f32x4){0.f, 0.f, 0.f, 0.f};
                S = mfma16(Kh[js], Qh[s], S);
                S = mfma16(Kh[js], Ql[s], S);
                S = mfma16(Kl[js], Qh[s], S);
                // element r: j = jb+js*16+quad*4+r, i = i0+s*16+l15
                size_t f4 = (((size_t)(h * 16 + w * 4 + s) * 16 +
                              (jb >> 4) + js) << 6) + quad * 16 + l15;
                float4 nb4 = *(const float4*)&nbP[f4 * 4];
                float4 mb4 = *(const float4*)&biasrow[jb + js * 16 + quad * 4];
                float p0 = __expf(S[0] + nb4.x + mb4.x - 4.0f);
                float p1 = __expf(S[1] + nb4.y + mb4.y - 4.0f);
                float p2 = __expf(S[2] + nb4.z + mb4.z - 4.0f);
                float p3 = __expf(S[3] + nb4.w + mb4.w - 4.0f);
                ls[s] += (p0 + p1) + (p2 + p3);
                PK4 hh, ll;
                hilo(p0, hh.b[0], ll.b[0]);
                hilo(p1, hh.b[1], ll.b[1]);
                hilo(p2, hh.b[2], ll.b[2]);
                hilo(p3, hh.b[3], ll.b[3]);
                *(uint2*)&ph[l15 * 40 + js * 16 + quad * 4] = hh.u2;
                *(uint2*)&pl[l15 * 40 + js * 16 + quad * 4] = ll.u2;
            }
            bf16x8 Ph = *(const bf16x8*)&ph[l15 * 40 + quad * 8];
            bf16x8 Pl = *(const bf16x8*)&pl[l15 * 40 + quad * 8];
            #pragma unroll
            for (int c = 0; c < 2; ++c) {
                O[s][c] = mfma16(Vh2[c], Ph, O[s][c]);
                O[s][c] = mfma16(Vl2[c], Ph, O[s][c]);
                O[s][c] = mfma16(Vh2[c], Pl, O[s][c]);
            }
        }
    }

    #pragma unroll
    for (int s = 0; s < 4; ++s) {
        ls[s] += __shfl_xor(ls[s], 16, 64);
        ls[s] += __shfl_xor(ls[s], 32, 64);
    }

    // epilogue: gate, stage hi/lo planes in LDS, contiguous 64B-run stores
    __syncthreads();   // vth/pb dead for all waves
    __bf16* const sth = (__bf16*)(smem + w * 10240);   // [64][40]
    __bf16* const stl = sth + 2560;
    #pragma unroll
    for (int s = 0; s < 4; ++s) {
        float inv = 1.0f / ls[s];
        #pragma unroll
        for (int c = 0; c < 2; ++c) {
            size_t gi = (rbase + i0 + s * 16 + l15) * CCH + ch0 + c * 16 + quad * 4;
            float4 g4 = *(const float4*)&gfp[gi];
            PK4 hh, ll;
            hilo(O[s][c][0] * inv * g4.x, hh.b[0], ll.b[0]);
            hilo(O[s][c][1] * inv * g4.y, hh.b[1], ll.b[1]);
            hilo(O[s][c][2] * inv * g4.z, hh.b[2], ll.b[2]);
            hilo(O[s][c][3] * inv * g4.w, hh.b[3], ll.b[3]);
            *(uint2*)&sth[(s * 16 + l15) * 40 + c * 16 + quad * 4] = hh.u2;
            *(uint2*)&stl[(s * 16 + l15) * 40 + c * 16 + quad * 4] = ll.u2;
        }
    }
    #pragma unroll
    for (int i = 0; i < 4; ++i) {
        int row = i * 16 + (lane >> 2);
        int c8 = lane & 3;
        uint4 hv = *(const uint4*)&sth[row * 40 + c8 * 8];
        uint4 lv = *(const uint4*)&stl[row * 40 + c8 * 8];
        size_t go = (rbase + i0 + row) * CCH + ch0 + c8 * 8;
        *(uint4*)&gth[go] = hv;
        *(uint4*)&gtl[go] = lv;
    }
}

// ---------------- output GEMM (MFMA): gated @ wo + bo -> fp32 ----------------
__global__ __launch_bounds__(256) void out_kernel(
    const __bf16* __restrict__ gth, const __bf16* __restrict__ gtl,
    const __bf16* __restrict__ wph, const __bf16* __restrict__ wpl,
    const float* __restrict__ bo, float* __restrict__ out)
{
    __shared__ float eps[4][16][132];
    const int t = threadIdx.x, w = t >> 6, lane = t & 63;
    const int l15 = lane & 15, quad = lane >> 4;
    const int r0 = blockIdx.x * 256 + w * 64;
    const __bf16* __restrict__ Bh = wph + (size_t)4 * 16384;
    const __bf16* __restrict__ Bl = wpl + (size_t)4 * 16384;

    f32x4 acc[4][8];
    #pragma unroll
    for (int s = 0; s < 4; ++s)
        #pragma unroll
        for (int n = 0; n < 8; ++n) acc[s][n] = (f32x4){0.f, 0.f, 0.f, 0.f};

    #pragma unroll
    for (int kf = 0; kf < 4; ++kf) {
        bf16x8 Ahf[4], Alf[4];
        #pragma unroll
        for (int s = 0; s < 4; ++s) {
            size_t idx = (size_t)(r0 + s * 16 + l15) * CCH + kf * 32 + quad * 8;
            Ahf[s] = *(const bf16x8*)&gth[idx];
            Alf[s] = *(const bf16x8*)&gtl[idx];
        }
        #pragma unroll
        for (int n = 0; n < 8; ++n) {
            size_t boff = (size_t)((n * 4 + kf) * 64 + lane) * 8;
            bf16x8 bh = *(const bf16x8*)&Bh[boff];
            bf16x8 bl = *(const bf16x8*)&Bl[boff];
            #pragma unroll
            for (int s = 0; s < 4; ++s) {
                acc[s][n] = mfma16(Ahf[s], bh, acc[s][n]);
                acc[s][n] = mfma16(Ahf[s], bl, acc[s][n]);
                acc[s][n] = mfma16(Alf[s], bh, acc[s][n]);
            }
        }
    }

    const int erow = lane >> 2;
    const int ecg0 = lane & 3;
    #pragma unroll 1
    for (int s = 0; s < 4; ++s) {
        #pragma unroll
        for (int n = 0; n < 8; ++n)
            #pragma unroll
            for (int r = 0; r < 4; ++r)
                eps[w][quad * 4 + r][n * 16 + l15] = acc[s][n][r];
        #pragma unroll
        for (int it = 0; it < 8; ++it) {
            int cg = ecg0 + it * 4;
            float4 v4 = *(const float4*)&eps[w][erow][cg * 4];
            float4 b4 = *(const float4*)&bo[cg * 4];
            v4.x += b4.x; v4.y += b4.y; v4.z += b4.z; v4.w += b4.w;
            *(float4*)&out[(size_t)(r0 + s * 16 + erow) * CCH + cg * 4] = v4;
        }
    }
}

extern "C" void kernel_launch(void* const* d_in, const int* in_sizes, int n_in,
                              void* d_out, int out_size, void* d_ws, size_t ws_size,
                              hipStream_t stream)
{
    const float* act  = (const float*)d_in[0];
    const float* mask = (const float*)d_in[1];
    const float* ln_g = (const float*)d_in[2];
    const float* ln_b = (const float*)d_in[3];
    const float* wq   = (const float*)d_in[4];
    const float* wk   = (const float*)d_in[5];
    const float* wv   = (const float*)d_in[6];
    const float* w2d  = (const float*)d_in[7];
    const float* wg   = (const float*)d_in[8];
    const float* bg   = (const float*)d_in[9];
    const float* wo   = (const float*)d_in[10];
    const float* bo   = (const float*)d_in[11];
    float* out = (float*)d_out;

    const size_t SZ = (size_t)NROWS * CCH;   // 8388608 elems
    __bf16* bws = (__bf16*)d_ws;
    __bf16* ah = bws;
    __bf16* al = bws + SZ;
    __bf16* qh = bws + 2 * SZ;
    __bf16* ql = bws + 3 * SZ;
    __bf16* kh = bws + 4 * SZ;
    __bf16* kl = bws + 5 * SZ;
    __bf16* vh = bws + 6 * SZ;
    __bf16* vl = bws + 7 * SZ;
    __bf16* gth = ah;   // a dead after proj; reuse
    __bf16* gtl = al;
    float* fws = (float*)(bws + 8 * SZ);
    float* gfp = fws;                          // SZ floats
    float* nbN = fws + SZ;                     // 4*NROWS floats
    float* nbP = nbN + 4 * NROWS;              // 4*NROWS floats
    __bf16* wph = (__bf16*)(nbP + 4 * NROWS);  // 5*16384 bf16
    __bf16* wpl = wph + 5 * 16384;

    prep_kernel<<<40, 256, 0, stream>>>(wq, wk, wv, wg, wo, wph, wpl);
    ln_nb_kernel<<<NROWS / 4, 256, 0, stream>>>(act, ln_g, ln_b, w2d, ah, al, nbN);
    nb_pack_kernel<<<256, 256, 0, stream>>>(nbN, nbP);
    proj_kernel<<<512, 256, 0, stream>>>(
        ah, al, wph, wpl, bg, qh, ql, kh, kl, vh, vl, gfp);
    attn_kernel<<<NRES * 4, 256, 0, stream>>>(
        qh, ql, kh, kl, vh, vl, gfp, mask, nbP, gth, gtl);
    out_kernel<<<256, 256, 0, stream>>>(gth, gtl, wph, wpl, bo, out);
}

// Round 6
// 249.650 us; speedup vs baseline: 2.5256x; 1.3347x over previous
//
#include <hip/hip_runtime.h>
#include <math.h>

// TriangleAttentionStartingNode: B=1, N=256, C=128, H=4, AC=32, fp32 in/out.
// R5: fuse ln + nb_pack + proj into lnproj_kernel (2048 small blocks, LN in
// LDS, wave=tensor proj, nb written directly in packed order). out_kernel
// re-gridded to 1024 blocks. attn unchanged (R5-proven). Rationale: R5
// counters showed proj latency/occupancy-bound (all pipes <35%), not
// traffic-bound; smaller blocks + fused producer removes 67MB traffic, two
// launches, and the 2-blocks/CU occupancy cap.

#define NRES 256
#define CCH  128
#define NROWS (NRES * NRES)          // 65536
#define FACTOR 0.17677669529663687f  // 1/sqrt(32)

typedef __attribute__((ext_vector_type(8))) __bf16 bf16x8;
typedef __attribute__((ext_vector_type(4))) float f32x4;

__device__ __forceinline__ f32x4 mfma16(bf16x8 a, bf16x8 b, f32x4 c) {
    return __builtin_amdgcn_mfma_f32_16x16x32_bf16(a, b, c, 0, 0, 0);
}

union PK4 { __bf16 b[4]; uint2 u2; };
union PK2 { __bf16 b[2]; unsigned int u; };

__device__ __forceinline__ void hilo(float x, __bf16& h, __bf16& l) {
    h = (__bf16)x;
    l = (__bf16)(x - (float)h);
}

// ---------------- weight prep: pack into B-frag layout ----------------
// frag slot gid = wid*2048 + nstrip*256 + kfrag*64 + lane; elem e:
// value = W[kfrag*32 + quad*8 + e][nstrip*16 + l15] * scale
__global__ __launch_bounds__(256) void prep_kernel(
    const float* __restrict__ wq, const float* __restrict__ wk,
    const float* __restrict__ wv, const float* __restrict__ wg,
    const float* __restrict__ wo,
    __bf16* __restrict__ wph, __bf16* __restrict__ wpl)
{
    const int gid = blockIdx.x * 256 + threadIdx.x;   // 0..10239
    const int wid = gid >> 11;
    const int rem = gid & 2047;
    const int nstrip = rem >> 8;
    const int kf = (rem >> 6) & 3;
    const int lane = rem & 63;
    const int l15 = lane & 15, quad = lane >> 4;
    const float* W = (wid == 0) ? wq : (wid == 1) ? wk :
                     (wid == 2) ? wv : (wid == 3) ? wg : wo;
    const float scale = (wid == 0) ? FACTOR : 1.0f;
    bf16x8 hb, lb;
    #pragma unroll
    for (int e = 0; e < 8; ++e) {
        int k = kf * 32 + quad * 8 + e;
        int n = nstrip * 16 + l15;
        float v = W[k * CCH + n] * scale;
        __bf16 h, l; hilo(v, h, l);
        hb[e] = h; lb[e] = l;
    }
    *(bf16x8*)&wph[(size_t)gid * 8] = hb;
    *(bf16x8*)&wpl[(size_t)gid * 8] = lb;
}

// ---------------- fused LN + nb + projection ----------------
// Block = 32 flat rows (same i, 32 consecutive j). Phase A: LN (8 thr/row)
// -> a hi/lo in LDS planes [32][136] + nb scatter in PACKED order. Phase B:
// wave w computes tensor w (q,k,v,g) for the 32 rows as 2 MFMA strips;
// epilogue stages per-wave planes, stores contiguous uint4/float4 runs.
__global__ __launch_bounds__(256) void lnproj_kernel(
    const float* __restrict__ act, const float* __restrict__ ln_g,
    const float* __restrict__ ln_b, const float* __restrict__ w2d,
    const __bf16* __restrict__ wph, const __bf16* __restrict__ wpl,
    const float* __restrict__ bg,
    __bf16* __restrict__ qh, __bf16* __restrict__ ql,
    __bf16* __restrict__ kh, __bf16* __restrict__ kl,
    __bf16* __restrict__ vh, __bf16* __restrict__ vl,
    float* __restrict__ gfp, float* __restrict__ nbP)
{
    __shared__ __align__(16) char smem[52224];
    __bf16* const aH = (__bf16*)smem;              // [32][136]
    __bf16* const aL = (__bf16*)(smem + 8704);     // [32][136]
    const int t = threadIdx.x, w = t >> 6, lane = t & 63;
    const int l15 = lane & 15, quad = lane >> 4;
    const int r0 = blockIdx.x * 32;

    // ---- Phase A: LayerNorm + nb ----
    {
        const int ridx = t >> 3, g = t & 7;        // 8 threads per row
        const int grow = r0 + ridx;
        const float* __restrict__ xp = act + (size_t)grow * CCH + g * 16;
        float4 x4[4];
        #pragma unroll
        for (int c = 0; c < 4; ++c) x4[c] = *(const float4*)(xp + c * 4);
        float s = 0.f, sq = 0.f;
        #pragma unroll
        for (int c = 0; c < 4; ++c) {
            s  += (x4[c].x + x4[c].y) + (x4[c].z + x4[c].w);
            sq += x4[c].x * x4[c].x + x4[c].y * x4[c].y +
                  x4[c].z * x4[c].z + x4[c].w * x4[c].w;
        }
        #pragma unroll
        for (int o = 1; o <= 4; o <<= 1) {
            s  += __shfl_xor(s, o, 64);
            sq += __shfl_xor(sq, o, 64);
        }
        float mu  = s * (1.0f / CCH);
        float var = fmaf(sq, 1.0f / CCH, -mu * mu);
        float rs  = rsqrtf(var + 1e-5f);
        float av[16];
        #pragma unroll
        for (int c = 0; c < 4; ++c) {
            float4 g4 = *(const float4*)&ln_g[g * 16 + c * 4];
            float4 b4 = *(const float4*)&ln_b[g * 16 + c * 4];
            float* xv = (float*)&x4[c];
            float* gv = (float*)&g4;
            float* bv = (float*)&b4;
            #pragma unroll
            for (int e = 0; e < 4; ++e)
                av[c * 4 + e] = fmaf((xv[e] - mu) * rs, gv[e], bv[e]);
        }
        // write bf16 hi/lo pairs into LDS planes (stride 136)
        #pragma unroll
        for (int p = 0; p < 8; ++p) {
            __bf16 h0, l0, h1, l1;
            hilo(av[p * 2], h0, l0);
            hilo(av[p * 2 + 1], h1, l1);
            PK2 ph; ph.b[0] = h0; ph.b[1] = h1;
            PK2 pl; pl.b[0] = l0; pl.b[1] = l1;
            int off = ridx * 136 + g * 16 + p * 2;
            *(unsigned int*)&aH[off] = ph.u;
            *(unsigned int*)&aL[off] = pl.u;
        }
        // nb partials (w2d is [C][4] row-major -> float4 per channel)
        float nb[4] = {0.f, 0.f, 0.f, 0.f};
        const float4* __restrict__ w2d4 = (const float4*)w2d;
        #pragma unroll
        for (int c = 0; c < 16; ++c) {
            float4 wv = w2d4[g * 16 + c];
            nb[0] = fmaf(av[c], wv.x, nb[0]);
            nb[1] = fmaf(av[c], wv.y, nb[1]);
            nb[2] = fmaf(av[c], wv.z, nb[2]);
            nb[3] = fmaf(av[c], wv.w, nb[3]);
        }
        #pragma unroll
        for (int o = 1; o <= 4; o <<= 1)
            #pragma unroll
            for (int hh = 0; hh < 4; ++hh)
                nb[hh] += __shfl_xor(nb[hh], o, 64);
        if (g == 0) {
            const int i = grow >> 8, j = grow & 255;
            #pragma unroll
            for (int hh = 0; hh < 4; ++hh) {
                size_t f = ((size_t)hh << 14) + ((size_t)(i >> 4) << 10) +
                           ((size_t)(j >> 4) << 6) + ((size_t)((j >> 2) & 3) << 4) +
                           (i & 15);
                nbP[f * 4 + (j & 3)] = nb[hh];
            }
        }
    }
    __syncthreads();

    // ---- Phase B: projection, wave w = tensor w ----
    const int tensor = w;
    const __bf16* __restrict__ Bh = wph + (size_t)tensor * 16384;
    const __bf16* __restrict__ Bl = wpl + (size_t)tensor * 16384;
    f32x4 acc0[8], acc1[8];
    #pragma unroll
    for (int n = 0; n < 8; ++n) {
        acc0[n] = (f32x4){0.f, 0.f, 0.f, 0.f};
        acc1[n] = (f32x4){0.f, 0.f, 0.f, 0.f};
    }
    #pragma unroll
    for (int kf = 0; kf < 4; ++kf) {
        const int ao = l15 * 136 + kf * 32 + quad * 8;
        bf16x8 aH0 = *(const bf16x8*)&aH[ao];
        bf16x8 aL0 = *(const bf16x8*)&aL[ao];
        bf16x8 aH1 = *(const bf16x8*)&aH[ao + 16 * 136];
        bf16x8 aL1 = *(const bf16x8*)&aL[ao + 16 * 136];
        #pragma unroll
        for (int n = 0; n < 8; ++n) {
            size_t boff = (size_t)((n * 4 + kf) * 64 + lane) * 8;
            bf16x8 bh = *(const bf16x8*)&Bh[boff];
            bf16x8 bl = *(const bf16x8*)&Bl[boff];
            acc0[n] = mfma16(aH0, bh, acc0[n]);
            acc0[n] = mfma16(aH0, bl, acc0[n]);
            acc0[n] = mfma16(aL0, bh, acc0[n]);
            acc1[n] = mfma16(aH1, bh, acc1[n]);
            acc1[n] = mfma16(aH1, bl, acc1[n]);
            acc1[n] = mfma16(aL1, bh, acc1[n]);
        }
    }

    char* const stg = smem + 17408 + w * 8704;   // per-wave staging
    if (tensor == 3) {
        float* const stf = (float*)stg;          // [16][132] fp32 (8448B<=8704)
        #pragma unroll 1
        for (int s = 0; s < 2; ++s) {
            f32x4* accp = s ? acc1 : acc0;
            #pragma unroll
            for (int n = 0; n < 8; ++n)
                #pragma unroll
                for (int r = 0; r < 4; ++r) {
                    float v = accp[n][r] + bg[n * 16 + l15];
                    stf[(quad * 4 + r) * 132 + n * 16 + l15] =
                        1.0f / (1.0f + __expf(-v));
                }
            #pragma unroll
            for (int i = 0; i < 8; ++i) {
                int row = i * 2 + (lane >> 5);
                int c4 = lane & 31;
                float4 v4 = *(const float4*)&stf[row * 132 + c4 * 4];
                *(float4*)&gfp[(size_t)(r0 + s * 16 + row) * CCH + c4 * 4] = v4;
            }
        }
    } else {
        __bf16* const sth = (__bf16*)stg;        // [16][136]
        __bf16* const stl = sth + 2176;          // [16][136]
        __bf16* const oh = (tensor == 0) ? qh : (tensor == 1) ? kh : vh;
        __bf16* const ol = (tensor == 0) ? ql : (tensor == 1) ? kl : vl;
        #pragma unroll 1
        for (int s = 0; s < 2; ++s) {
            f32x4* accp = s ? acc1 : acc0;
            #pragma unroll
            for (int n = 0; n < 8; ++n)
                #pragma unroll
                for (int r = 0; r < 4; ++r) {
                    __bf16 h, l; hilo(accp[n][r], h, l);
                    sth[(quad * 4 + r) * 136 + n * 16 + l15] = h;
                    stl[(quad * 4 + r) * 136 + n * 16 + l15] = l;
                }
            #pragma unroll
            for (int i = 0; i < 4; ++i) {
                int row = i * 4 + (lane >> 4);
                int c8 = lane & 15;
                uint4 hv = *(const uint4*)&sth[row * 136 + c8 * 8];
                uint4 lv = *(const uint4*)&stl[row * 136 + c8 * 8];
                size_t go = (size_t)(r0 + s * 16 + row) * CCH + c8 * 8;
                *(uint4*)&oh[go] = hv;
                *(uint4*)&ol[go] = lv;
            }
        }
    }
}

// ---------------- attention: S^T path, fixed-shift softmax ----------------
__global__ __launch_bounds__(256) void attn_kernel(
    const __bf16* __restrict__ qh, const __bf16* __restrict__ ql,
    const __bf16* __restrict__ kh, const __bf16* __restrict__ kl,
    const __bf16* __restrict__ vh, const __bf16* __restrict__ vl,
    const float* __restrict__ gfp, const float* __restrict__ mask,
    const float* __restrict__ nbP,
    __bf16* __restrict__ gth, __bf16* __restrict__ gtl)
{
    __shared__ __align__(16) char smem[45056];
    __bf16* const vth = (__bf16*)smem;               // [32][264]
    __bf16* const vtl = (__bf16*)(smem + 16896);     // [32][264]
    __bf16* const pbb = (__bf16*)(smem + 33792);     // [4][2][16][40]
    float*  const biasrow = (float*)(smem + 44032);  // [256]
    const int t = threadIdx.x, w = t >> 6, lane = t & 63;
    const int l15 = lane & 15, quad = lane >> 4;
    const int mrow = blockIdx.x >> 2, h = blockIdx.x & 3;
    const size_t rbase = (size_t)mrow * NRES;
    const int ch0 = h * 32;

    biasrow[t] = 1e9f * (mask[mrow * NRES + t] - 1.0f);

    // V^T staging (hi/lo)
    #pragma unroll
    for (int it = 0; it < 4; ++it) {
        int f = t + it * 256;
        int j = f >> 2, cg = f & 3;
        bf16x8 hv = *(const bf16x8*)&vh[(rbase + j) * CCH + ch0 + cg * 8];
        bf16x8 lv = *(const bf16x8*)&vl[(rbase + j) * CCH + ch0 + cg * 8];
        #pragma unroll
        for (int e = 0; e < 8; ++e) {
            vth[(cg * 8 + e) * 264 + j] = hv[e];
            vtl[(cg * 8 + e) * 264 + j] = lv[e];
        }
    }
    __syncthreads();

    const int i0 = w * 64;
    bf16x8 Qh[4], Ql[4];
    #pragma unroll
    for (int s = 0; s < 4; ++s) {
        size_t idx = (rbase + i0 + s * 16 + l15) * CCH + ch0 + quad * 8;
        Qh[s] = *(const bf16x8*)&qh[idx];
        Ql[s] = *(const bf16x8*)&ql[idx];
    }

    f32x4 O[4][2];
    float ls[4] = {0.f, 0.f, 0.f, 0.f};
    #pragma unroll
    for (int s = 0; s < 4; ++s) {
        O[s][0] = (f32x4){0.f, 0.f, 0.f, 0.f};
        O[s][1] = (f32x4){0.f, 0.f, 0.f, 0.f};
    }
    __bf16* const ph = pbb + w * 1280;
    __bf16* const pl = ph + 640;

    for (int jb = 0; jb < NRES; jb += 32) {
        bf16x8 Kh[2], Kl[2];
        #pragma unroll
        for (int js = 0; js < 2; ++js) {
            size_t idx = (rbase + jb + js * 16 + l15) * CCH + ch0 + quad * 8;
            Kh[js] = *(const bf16x8*)&kh[idx];
            Kl[js] = *(const bf16x8*)&kl[idx];
        }
        bf16x8 Vh2[2], Vl2[2];
        #pragma unroll
        for (int c = 0; c < 2; ++c) {
            Vh2[c] = *(const bf16x8*)&vth[(c * 16 + l15) * 264 + jb + quad * 8];
            Vl2[c] = *(const bf16x8*)&vtl[(c * 16 + l15) * 264 + jb + quad * 8];
        }
        #pragma unroll
        for (int s = 0; s < 4; ++s) {
            #pragma unroll
            for (int js = 0; js < 2; ++js) {
                f32x4 S = (f32x4){0.f, 0.f, 0.f, 0.f};
                S = mfma16(Kh[js], Qh[s], S);
                S = mfma16(Kh[js], Ql[s], S);
                S = mfma16(Kl[js], Qh[s], S);
                // element r: j = jb+js*16+quad*4+r, i = i0+s*16+l15
                size_t f4 = (((size_t)(h * 16 + w * 4 + s) * 16 +
                              (jb >> 4) + js) << 6) + quad * 16 + l15;
                float4 nb4 = *(const float4*)&nbP[f4 * 4];
                float4 mb4 = *(const float4*)&biasrow[jb + js * 16 + quad * 4];
                float p0 = __expf(S[0] + nb4.x + mb4.x - 4.0f);
                float p1 = __expf(S[1] + nb4.y + mb4.y - 4.0f);
                float p2 = __expf(S[2] + nb4.z + mb4.z - 4.0f);
                float p3 = __expf(S[3] + nb4.w + mb4.w - 4.0f);
                ls[s] += (p0 + p1) + (p2 + p3);
                PK4 hh, ll;
                hilo(p0, hh.b[0], ll.b[0]);
                hilo(p1, hh.b[1], ll.b[1]);
                hilo(p2, hh.b[2], ll.b[2]);
                hilo(p3, hh.b[3], ll.b[3]);
                *(uint2*)&ph[l15 * 40 + js * 16 + quad * 4] = hh.u2;
                *(uint2*)&pl[l15 * 40 + js * 16 + quad * 4] = ll.u2;
            }
            bf16x8 Ph = *(const bf16x8*)&ph[l15 * 40 + quad * 8];
            bf16x8 Pl = *(const bf16x8*)&pl[l15 * 40 + quad * 8];
            #pragma unroll
            for (int c = 0; c < 2; ++c) {
                O[s][c] = mfma16(Vh2[c], Ph, O[s][c]);
                O[s][c] = mfma16(Vl2[c], Ph, O[s][c]);
                O[s][c] = mfma16(Vh2[c], Pl, O[s][c]);
            }
        }
    }

    #pragma unroll
    for (int s = 0; s < 4; ++s) {
        ls[s] += __shfl_xor(ls[s], 16, 64);
        ls[s] += __shfl_xor(ls[s], 32, 64);
    }

    // epilogue: gate, stage hi/lo planes in LDS, contiguous 64B-run stores
    __syncthreads();   // vth/pb dead for all waves
    __bf16* const sth = (__bf16*)(smem + w * 10240);   // [64][40]
    __bf16* const stl = sth + 2560;
    #pragma unroll
    for (int s = 0; s < 4; ++s) {
        float inv = 1.0f / ls[s];
        #pragma unroll
        for (int c = 0; c < 2; ++c) {
            size_t gi = (rbase + i0 + s * 16 + l15) * CCH + ch0 + c * 16 + quad * 4;
            float4 g4 = *(const float4*)&gfp[gi];
            PK4 hh, ll;
            hilo(O[s][c][0] * inv * g4.x, hh.b[0], ll.b[0]);
            hilo(O[s][c][1] * inv * g4.y, hh.b[1], ll.b[1]);
            hilo(O[s][c][2] * inv * g4.z, hh.b[2], ll.b[2]);
            hilo(O[s][c][3] * inv * g4.w, hh.b[3], ll.b[3]);
            *(uint2*)&sth[(s * 16 + l15) * 40 + c * 16 + quad * 4] = hh.u2;
            *(uint2*)&stl[(s * 16 + l15) * 40 + c * 16 + quad * 4] = ll.u2;
        }
    }
    #pragma unroll
    for (int i = 0; i < 4; ++i) {
        int row = i * 16 + (lane >> 2);
        int c8 = lane & 3;
        uint4 hv = *(const uint4*)&sth[row * 40 + c8 * 8];
        uint4 lv = *(const uint4*)&stl[row * 40 + c8 * 8];
        size_t go = (rbase + i0 + row) * CCH + ch0 + c8 * 8;
        *(uint4*)&gth[go] = hv;
        *(uint4*)&gtl[go] = lv;
    }
}

// ---------------- output GEMM (MFMA): gated @ wo + bo -> fp32 ----------------
// 1024 blocks x 64 rows; wave = one 16-row strip.
__global__ __launch_bounds__(256) void out_kernel(
    const __bf16* __restrict__ gth, const __bf16* __restrict__ gtl,
    const __bf16* __restrict__ wph, const __bf16* __restrict__ wpl,
    const float* __restrict__ bo, float* __restrict__ out)
{
    __shared__ __align__(16) float eps[4][16 * 132];
    const int t = threadIdx.x, w = t >> 6, lane = t & 63;
    const int l15 = lane & 15, quad = lane >> 4;
    const int r0 = blockIdx.x * 64 + w * 16;
    const __bf16* __restrict__ Bh = wph + (size_t)4 * 16384;
    const __bf16* __restrict__ Bl = wpl + (size_t)4 * 16384;

    f32x4 acc[8];
    #pragma unroll
    for (int n = 0; n < 8; ++n) acc[n] = (f32x4){0.f, 0.f, 0.f, 0.f};

    #pragma unroll
    for (int kf = 0; kf < 4; ++kf) {
        size_t idx = (size_t)(r0 + l15) * CCH + kf * 32 + quad * 8;
        bf16x8 Ahf = *(const bf16x8*)&gth[idx];
        bf16x8 Alf = *(const bf16x8*)&gtl[idx];
        #pragma unroll
        for (int n = 0; n < 8; ++n) {
            size_t boff = (size_t)((n * 4 + kf) * 64 + lane) * 8;
            bf16x8 bh = *(const bf16x8*)&Bh[boff];
            bf16x8 bl = *(const bf16x8*)&Bl[boff];
            acc[n] = mfma16(Ahf, bh, acc[n]);
            acc[n] = mfma16(Ahf, bl, acc[n]);
            acc[n] = mfma16(Alf, bh, acc[n]);
        }
    }

    #pragma unroll
    for (int n = 0; n < 8; ++n)
        #pragma unroll
        for (int r = 0; r < 4; ++r)
            eps[w][(quad * 4 + r) * 132 + n * 16 + l15] = acc[n][r];
    const int erow = lane >> 2;
    const int ecg0 = lane & 3;
    #pragma unroll
    for (int it = 0; it < 8; ++it) {
        int cg = ecg0 + it * 4;
        float4 v4 = *(const float4*)&eps[w][erow * 132 + cg * 4];
        float4 b4 = *(const float4*)&bo[cg * 4];
        v4.x += b4.x; v4.y += b4.y; v4.z += b4.z; v4.w += b4.w;
        *(float4*)&out[(size_t)(r0 + erow) * CCH + cg * 4] = v4;
    }
}

extern "C" void kernel_launch(void* const* d_in, const int* in_sizes, int n_in,
                              void* d_out, int out_size, void* d_ws, size_t ws_size,
                              hipStream_t stream)
{
    const float* act  = (const float*)d_in[0];
    const float* mask = (const float*)d_in[1];
    const float* ln_g = (const float*)d_in[2];
    const float* ln_b = (const float*)d_in[3];
    const float* wq   = (const float*)d_in[4];
    const float* wk   = (const float*)d_in[5];
    const float* wv   = (const float*)d_in[6];
    const float* w2d  = (const float*)d_in[7];
    const float* wg   = (const float*)d_in[8];
    const float* bg   = (const float*)d_in[9];
    const float* wo   = (const float*)d_in[10];
    const float* bo   = (const float*)d_in[11];
    float* out = (float*)d_out;

    const size_t SZ = (size_t)NROWS * CCH;   // 8388608 elems
    __bf16* bws = (__bf16*)d_ws;
    __bf16* qh  = bws;
    __bf16* ql  = bws + SZ;
    __bf16* kh  = bws + 2 * SZ;
    __bf16* kl  = bws + 3 * SZ;
    __bf16* vh  = bws + 4 * SZ;
    __bf16* vl  = bws + 5 * SZ;
    __bf16* gth = bws + 6 * SZ;
    __bf16* gtl = bws + 7 * SZ;
    float* fws = (float*)(bws + 8 * SZ);
    float* gfp = fws;                          // SZ floats
    float* nbP = fws + SZ;                     // 4*NROWS floats
    __bf16* wph = (__bf16*)(nbP + 4 * NROWS);  // 5*16384 bf16
    __bf16* wpl = wph + 5 * 16384;

    prep_kernel<<<40, 256, 0, stream>>>(wq, wk, wv, wg, wo, wph, wpl);
    lnproj_kernel<<<2048, 256, 0, stream>>>(
        act, ln_g, ln_b, w2d, wph, wpl, bg,
        qh, ql, kh, kl, vh, vl, gfp, nbP);
    attn_kernel<<<NRES * 4, 256, 0, stream>>>(
        qh, ql, kh, kl, vh, vl, gfp, mask, nbP, gth, gtl);
    out_kernel<<<1024, 256, 0, stream>>>(gth, gtl, wph, wpl, bo, out);
}

// Round 7
// 204.064 us; speedup vs baseline: 3.0898x; 1.2234x over previous
//
#include <hip/hip_runtime.h>
#include <hip/hip_fp16.h>
#include <math.h>

// TriangleAttentionStartingNode: B=1, N=256, C=128, H=4, AC=32, fp32 in/out.
// R6: precision-lite pipeline. Error analysis: (a) softmax path is
// insensitive to S errors (|S|~0.05, dP/P = dS ~ 3e-4 -> out < 1e-6);
// (b) out-proj contracts 128 ch with wo~0.02 -> x0.226 attenuation of all
// per-channel upstream errors. So: q/k/v/g GEMMs and storage single bf16,
// P single bf16, g fp16; ONLY the final out GEMM keeps the hi/lo split
// (its error hits the output unattenuated). Halves traffic and MFMA count
// in both hot kernels; LDS 52->26 KB (lnproj), 45->23 KB (attn).

#define NRES 256
#define CCH  128
#define NROWS (NRES * NRES)          // 65536
#define FACTOR 0.17677669529663687f  // 1/sqrt(32)

typedef __attribute__((ext_vector_type(8))) __bf16 bf16x8;
typedef __attribute__((ext_vector_type(4))) float f32x4;

__device__ __forceinline__ f32x4 mfma16(bf16x8 a, bf16x8 b, f32x4 c) {
    return __builtin_amdgcn_mfma_f32_16x16x32_bf16(a, b, c, 0, 0, 0);
}

union PK4 { __bf16 b[4]; uint2 u2; };
union PK2 { __bf16 b[2]; unsigned int u; };

__device__ __forceinline__ void hilo(float x, __bf16& h, __bf16& l) {
    h = (__bf16)x;
    l = (__bf16)(x - (float)h);
}

// ---------------- weight prep: pack into B-frag layout ----------------
// hi planes used by lnproj (single-MFMA GEMMs); lo planes only read for wo.
__global__ __launch_bounds__(256) void prep_kernel(
    const float* __restrict__ wq, const float* __restrict__ wk,
    const float* __restrict__ wv, const float* __restrict__ wg,
    const float* __restrict__ wo,
    __bf16* __restrict__ wph, __bf16* __restrict__ wpl)
{
    const int gid = blockIdx.x * 256 + threadIdx.x;   // 0..10239
    const int wid = gid >> 11;
    const int rem = gid & 2047;
    const int nstrip = rem >> 8;
    const int kf = (rem >> 6) & 3;
    const int lane = rem & 63;
    const int l15 = lane & 15, quad = lane >> 4;
    const float* W = (wid == 0) ? wq : (wid == 1) ? wk :
                     (wid == 2) ? wv : (wid == 3) ? wg : wo;
    const float scale = (wid == 0) ? FACTOR : 1.0f;
    bf16x8 hb, lb;
    #pragma unroll
    for (int e = 0; e < 8; ++e) {
        int k = kf * 32 + quad * 8 + e;
        int n = nstrip * 16 + l15;
        float v = W[k * CCH + n] * scale;
        __bf16 h, l; hilo(v, h, l);
        hb[e] = h; lb[e] = l;
    }
    *(bf16x8*)&wph[(size_t)gid * 8] = hb;
    *(bf16x8*)&wpl[(size_t)gid * 8] = lb;
}

// ---------------- fused LN + nb + projection (single-bf16) ----------------
__global__ __launch_bounds__(256) void lnproj_kernel(
    const float* __restrict__ act, const float* __restrict__ ln_g,
    const float* __restrict__ ln_b, const float* __restrict__ w2d,
    const __bf16* __restrict__ wph, const float* __restrict__ bg,
    __bf16* __restrict__ qb, __bf16* __restrict__ kb,
    __bf16* __restrict__ vb, __half* __restrict__ gfh,
    float* __restrict__ nbP)
{
    __shared__ __align__(16) char smem[26112];
    __bf16* const aH = (__bf16*)smem;              // [32][136]
    const int t = threadIdx.x, w = t >> 6, lane = t & 63;
    const int l15 = lane & 15, quad = lane >> 4;
    const int r0 = blockIdx.x * 32;

    // ---- Phase A: LayerNorm + nb ----
    {
        const int ridx = t >> 3, g = t & 7;        // 8 threads per row
        const int grow = r0 + ridx;
        const float* __restrict__ xp = act + (size_t)grow * CCH + g * 16;
        float4 x4[4];
        #pragma unroll
        for (int c = 0; c < 4; ++c) x4[c] = *(const float4*)(xp + c * 4);
        float s = 0.f, sq = 0.f;
        #pragma unroll
        for (int c = 0; c < 4; ++c) {
            s  += (x4[c].x + x4[c].y) + (x4[c].z + x4[c].w);
            sq += x4[c].x * x4[c].x + x4[c].y * x4[c].y +
                  x4[c].z * x4[c].z + x4[c].w * x4[c].w;
        }
        #pragma unroll
        for (int o = 1; o <= 4; o <<= 1) {
            s  += __shfl_xor(s, o, 64);
            sq += __shfl_xor(sq, o, 64);
        }
        float mu  = s * (1.0f / CCH);
        float var = fmaf(sq, 1.0f / CCH, -mu * mu);
        float rs  = rsqrtf(var + 1e-5f);
        float av[16];
        #pragma unroll
        for (int c = 0; c < 4; ++c) {
            float4 g4 = *(const float4*)&ln_g[g * 16 + c * 4];
            float4 b4 = *(const float4*)&ln_b[g * 16 + c * 4];
            float* xv = (float*)&x4[c];
            float* gv = (float*)&g4;
            float* bv = (float*)&b4;
            #pragma unroll
            for (int e = 0; e < 4; ++e)
                av[c * 4 + e] = fmaf((xv[e] - mu) * rs, gv[e], bv[e]);
        }
        #pragma unroll
        for (int p = 0; p < 8; ++p) {
            PK2 ph;
            ph.b[0] = (__bf16)av[p * 2];
            ph.b[1] = (__bf16)av[p * 2 + 1];
            *(unsigned int*)&aH[ridx * 136 + g * 16 + p * 2] = ph.u;
        }
        float nb[4] = {0.f, 0.f, 0.f, 0.f};
        const float4* __restrict__ w2d4 = (const float4*)w2d;
        #pragma unroll
        for (int c = 0; c < 16; ++c) {
            float4 wv = w2d4[g * 16 + c];
            nb[0] = fmaf(av[c], wv.x, nb[0]);
            nb[1] = fmaf(av[c], wv.y, nb[1]);
            nb[2] = fmaf(av[c], wv.z, nb[2]);
            nb[3] = fmaf(av[c], wv.w, nb[3]);
        }
        #pragma unroll
        for (int o = 1; o <= 4; o <<= 1)
            #pragma unroll
            for (int hh = 0; hh < 4; ++hh)
                nb[hh] += __shfl_xor(nb[hh], o, 64);
        if (g == 0) {
            const int i = grow >> 8, j = grow & 255;
            #pragma unroll
            for (int hh = 0; hh < 4; ++hh) {
                size_t f = ((size_t)hh << 14) + ((size_t)(i >> 4) << 10) +
                           ((size_t)(j >> 4) << 6) + ((size_t)((j >> 2) & 3) << 4) +
                           (i & 15);
                nbP[f * 4 + (j & 3)] = nb[hh];
            }
        }
    }
    __syncthreads();

    // ---- Phase B: projection, wave w = tensor w (single MFMA per frag) ----
    const int tensor = w;
    const __bf16* __restrict__ Bh = wph + (size_t)tensor * 16384;
    f32x4 acc0[8], acc1[8];
    #pragma unroll
    for (int n = 0; n < 8; ++n) {
        acc0[n] = (f32x4){0.f, 0.f, 0.f, 0.f};
        acc1[n] = (f32x4){0.f, 0.f, 0.f, 0.f};
    }
    #pragma unroll
    for (int kf = 0; kf < 4; ++kf) {
        const int ao = l15 * 136 + kf * 32 + quad * 8;
        bf16x8 A0 = *(const bf16x8*)&aH[ao];
        bf16x8 A1 = *(const bf16x8*)&aH[ao + 16 * 136];
        #pragma unroll
        for (int n = 0; n < 8; ++n) {
            bf16x8 bh = *(const bf16x8*)&Bh[(size_t)((n * 4 + kf) * 64 + lane) * 8];
            acc0[n] = mfma16(A0, bh, acc0[n]);
            acc1[n] = mfma16(A1, bh, acc1[n]);
        }
    }

    char* const stg = smem + 8704 + w * 4352;    // per-wave [16][136] 2B plane
    if (tensor == 3) {
        __half* const sth = (__half*)stg;
        #pragma unroll 1
        for (int s = 0; s < 2; ++s) {
            f32x4* accp = s ? acc1 : acc0;
            #pragma unroll
            for (int n = 0; n < 8; ++n)
                #pragma unroll
                for (int r = 0; r < 4; ++r) {
                    float v = accp[n][r] + bg[n * 16 + l15];
                    sth[(quad * 4 + r) * 136 + n * 16 + l15] =
                        (__half)(1.0f / (1.0f + __expf(-v)));
                }
            #pragma unroll
            for (int i = 0; i < 4; ++i) {
                int row = i * 4 + (lane >> 4);
                int c8 = lane & 15;
                uint4 hv = *(const uint4*)&sth[row * 136 + c8 * 8];
                *(uint4*)&gfh[(size_t)(r0 + s * 16 + row) * CCH + c8 * 8] = hv;
            }
        }
    } else {
        __bf16* const sth = (__bf16*)stg;
        __bf16* const oh = (tensor == 0) ? qb : (tensor == 1) ? kb : vb;
        #pragma unroll 1
        for (int s = 0; s < 2; ++s) {
            f32x4* accp = s ? acc1 : acc0;
            #pragma unroll
            for (int n = 0; n < 8; ++n)
                #pragma unroll
                for (int r = 0; r < 4; ++r)
                    sth[(quad * 4 + r) * 136 + n * 16 + l15] = (__bf16)accp[n][r];
            #pragma unroll
            for (int i = 0; i < 4; ++i) {
                int row = i * 4 + (lane >> 4);
                int c8 = lane & 15;
                uint4 hv = *(const uint4*)&sth[row * 136 + c8 * 8];
                *(uint4*)&oh[(size_t)(r0 + s * 16 + row) * CCH + c8 * 8] = hv;
            }
        }
    }
}

// ---------------- attention (single-bf16 S^T path) ----------------
__global__ __launch_bounds__(256) void attn_kernel(
    const __bf16* __restrict__ qb, const __bf16* __restrict__ kb,
    const __bf16* __restrict__ vb, const __half* __restrict__ gfh,
    const float* __restrict__ mask, const float* __restrict__ nbP,
    __bf16* __restrict__ gth, __bf16* __restrict__ gtl)
{
    __shared__ __align__(16) char smem[23040];
    __bf16* const vth = (__bf16*)smem;               // [32][264] = 16896B
    __bf16* const pbb = (__bf16*)(smem + 16896);     // [4][16][40] = 5120B
    float*  const biasrow = (float*)(smem + 22016);  // [256]
    const int t = threadIdx.x, w = t >> 6, lane = t & 63;
    const int l15 = lane & 15, quad = lane >> 4;
    const int mrow = blockIdx.x >> 2, h = blockIdx.x & 3;
    const size_t rbase = (size_t)mrow * NRES;
    const int ch0 = h * 32;

    biasrow[t] = 1e9f * (mask[mrow * NRES + t] - 1.0f);

    // V^T staging (single plane)
    #pragma unroll
    for (int it = 0; it < 4; ++it) {
        int f = t + it * 256;
        int j = f >> 2, cg = f & 3;
        bf16x8 hv = *(const bf16x8*)&vb[(rbase + j) * CCH + ch0 + cg * 8];
        #pragma unroll
        for (int e = 0; e < 8; ++e)
            vth[(cg * 8 + e) * 264 + j] = hv[e];
    }
    __syncthreads();

    const int i0 = w * 64;
    bf16x8 Qh[4];
    #pragma unroll
    for (int s = 0; s < 4; ++s)
        Qh[s] = *(const bf16x8*)&qb[(rbase + i0 + s * 16 + l15) * CCH + ch0 + quad * 8];

    f32x4 O[4][2];
    float ls[4] = {0.f, 0.f, 0.f, 0.f};
    #pragma unroll
    for (int s = 0; s < 4; ++s) {
        O[s][0] = (f32x4){0.f, 0.f, 0.f, 0.f};
        O[s][1] = (f32x4){0.f, 0.f, 0.f, 0.f};
    }
    __bf16* const ph = pbb + w * 640;

    for (int jb = 0; jb < NRES; jb += 32) {
        bf16x8 Kh[2];
        #pragma unroll
        for (int js = 0; js < 2; ++js)
            Kh[js] = *(const bf16x8*)&kb[(rbase + jb + js * 16 + l15) * CCH + ch0 + quad * 8];
        bf16x8 Vh2[2];
        #pragma unroll
        for (int c = 0; c < 2; ++c)
            Vh2[c] = *(const bf16x8*)&vth[(c * 16 + l15) * 264 + jb + quad * 8];
        #pragma unroll
        for (int s = 0; s < 4; ++s) {
            #pragma unroll
            for (int js = 0; js < 2; ++js) {
                f32x4 S = (f32x4){0.f, 0.f, 0.f, 0.f};
                S = mfma16(Kh[js], Qh[s], S);
                size_t f4 = (((size_t)(h * 16 + w * 4 + s) * 16 +
                              (jb >> 4) + js) << 6) + quad * 16 + l15;
                float4 nb4 = *(const float4*)&nbP[f4 * 4];
                float4 mb4 = *(const float4*)&biasrow[jb + js * 16 + quad * 4];
                float p0 = __expf(S[0] + nb4.x + mb4.x - 4.0f);
                float p1 = __expf(S[1] + nb4.y + mb4.y - 4.0f);
                float p2 = __expf(S[2] + nb4.z + mb4.z - 4.0f);
                float p3 = __expf(S[3] + nb4.w + mb4.w - 4.0f);
                ls[s] += (p0 + p1) + (p2 + p3);
                PK4 hh;
                hh.b[0] = (__bf16)p0; hh.b[1] = (__bf16)p1;
                hh.b[2] = (__bf16)p2; hh.b[3] = (__bf16)p3;
                *(uint2*)&ph[l15 * 40 + js * 16 + quad * 4] = hh.u2;
            }
            bf16x8 Ph = *(const bf16x8*)&ph[l15 * 40 + quad * 8];
            #pragma unroll
            for (int c = 0; c < 2; ++c)
                O[s][c] = mfma16(Vh2[c], Ph, O[s][c]);
        }
    }

    #pragma unroll
    for (int s = 0; s < 4; ++s) {
        ls[s] += __shfl_xor(ls[s], 16, 64);
        ls[s] += __shfl_xor(ls[s], 32, 64);
    }

    // epilogue: gate (fp16 g), hi/lo output via two-pass per-wave staging
    float ov[4][2][4];
    #pragma unroll
    for (int s = 0; s < 4; ++s) {
        float inv = 1.0f / ls[s];
        #pragma unroll
        for (int c = 0; c < 2; ++c) {
            size_t gi = (rbase + i0 + s * 16 + l15) * CCH + ch0 + c * 16 + quad * 4;
            uint2 gu = *(const uint2*)&gfh[gi];
            const __half* gh = (const __half*)&gu;
            #pragma unroll
            for (int r = 0; r < 4; ++r)
                ov[s][c][r] = O[s][c][r] * inv * (float)gh[r];
        }
    }
    __syncthreads();   // vth/pb dead for all waves
    __bf16* const stp = (__bf16*)(smem + w * 5120);   // [64][40]
    #pragma unroll
    for (int s = 0; s < 4; ++s)
        #pragma unroll
        for (int c = 0; c < 2; ++c) {
            PK4 hh;
            #pragma unroll
            for (int r = 0; r < 4; ++r) hh.b[r] = (__bf16)ov[s][c][r];
            *(uint2*)&stp[(s * 16 + l15) * 40 + c * 16 + quad * 4] = hh.u2;
        }
    #pragma unroll
    for (int i = 0; i < 4; ++i) {
        int row = i * 16 + (lane >> 2);
        int c8 = lane & 3;
        uint4 hv = *(const uint4*)&stp[row * 40 + c8 * 8];
        *(uint4*)&gth[(rbase + i0 + row) * CCH + ch0 + c8 * 8] = hv;
    }
    #pragma unroll
    for (int s = 0; s < 4; ++s)
        #pragma unroll
        for (int c = 0; c < 2; ++c) {
            PK4 ll;
            #pragma unroll
            for (int r = 0; r < 4; ++r) {
                __bf16 hv = (__bf16)ov[s][c][r];
                ll.b[r] = (__bf16)(ov[s][c][r] - (float)hv);
            }
            *(uint2*)&stp[(s * 16 + l15) * 40 + c * 16 + quad * 4] = ll.u2;
        }
    #pragma unroll
    for (int i = 0; i < 4; ++i) {
        int row = i * 16 + (lane >> 2);
        int c8 = lane & 3;
        uint4 lv = *(const uint4*)&stp[row * 40 + c8 * 8];
        *(uint4*)&gtl[(rbase + i0 + row) * CCH + ch0 + c8 * 8] = lv;
    }
}

// ---------------- output GEMM (split MFMA): gated @ wo + bo -> fp32 --------
__global__ __launch_bounds__(256) void out_kernel(
    const __bf16* __restrict__ gth, const __bf16* __restrict__ gtl,
    const __bf16* __restrict__ wph, const __bf16* __restrict__ wpl,
    const float* __restrict__ bo, float* __restrict__ out)
{
    __shared__ __align__(16) float eps[4][16 * 132];
    const int t = threadIdx.x, w = t >> 6, lane = t & 63;
    const int l15 = lane & 15, quad = lane >> 4;
    const int r0 = blockIdx.x * 64 + w * 16;
    const __bf16* __restrict__ Bh = wph + (size_t)4 * 16384;
    const __bf16* __restrict__ Bl = wpl + (size_t)4 * 16384;

    f32x4 acc[8];
    #pragma unroll
    for (int n = 0; n < 8; ++n) acc[n] = (f32x4){0.f, 0.f, 0.f, 0.f};

    #pragma unroll
    for (int kf = 0; kf < 4; ++kf) {
        size_t idx = (size_t)(r0 + l15) * CCH + kf * 32 + quad * 8;
        bf16x8 Ahf = *(const bf16x8*)&gth[idx];
        bf16x8 Alf = *(const bf16x8*)&gtl[idx];
        #pragma unroll
        for (int n = 0; n < 8; ++n) {
            size_t boff = (size_t)((n * 4 + kf) * 64 + lane) * 8;
            bf16x8 bh = *(const bf16x8*)&Bh[boff];
            bf16x8 bl = *(const bf16x8*)&Bl[boff];
            acc[n] = mfma16(Ahf, bh, acc[n]);
            acc[n] = mfma16(Ahf, bl, acc[n]);
            acc[n] = mfma16(Alf, bh, acc[n]);
        }
    }

    #pragma unroll
    for (int n = 0; n < 8; ++n)
        #pragma unroll
        for (int r = 0; r < 4; ++r)
            eps[w][(quad * 4 + r) * 132 + n * 16 + l15] = acc[n][r];
    const int erow = lane >> 2;
    const int ecg0 = lane & 3;
    #pragma unroll
    for (int it = 0; it < 8; ++it) {
        int cg = ecg0 + it * 4;
        float4 v4 = *(const float4*)&eps[w][erow * 132 + cg * 4];
        float4 b4 = *(const float4*)&bo[cg * 4];
        v4.x += b4.x; v4.y += b4.y; v4.z += b4.z; v4.w += b4.w;
        *(float4*)&out[(size_t)(r0 + erow) * CCH + cg * 4] = v4;
    }
}

extern "C" void kernel_launch(void* const* d_in, const int* in_sizes, int n_in,
                              void* d_out, int out_size, void* d_ws, size_t ws_size,
                              hipStream_t stream)
{
    const float* act  = (const float*)d_in[0];
    const float* mask = (const float*)d_in[1];
    const float* ln_g = (const float*)d_in[2];
    const float* ln_b = (const float*)d_in[3];
    const float* wq   = (const float*)d_in[4];
    const float* wk   = (const float*)d_in[5];
    const float* wv   = (const float*)d_in[6];
    const float* w2d  = (const float*)d_in[7];
    const float* wg   = (const float*)d_in[8];
    const float* bg   = (const float*)d_in[9];
    const float* wo   = (const float*)d_in[10];
    const float* bo   = (const float*)d_in[11];
    float* out = (float*)d_out;

    const size_t SZ = (size_t)NROWS * CCH;   // 8388608 elems
    __bf16* bws = (__bf16*)d_ws;
    __bf16* qb  = bws;
    __bf16* kb  = bws + SZ;
    __bf16* vb  = bws + 2 * SZ;
    __bf16* gth = bws + 3 * SZ;
    __bf16* gtl = bws + 4 * SZ;
    __half* gfh = (__half*)(bws + 5 * SZ);     // SZ halves
    float* nbP = (float*)(bws + 6 * SZ);       // 4*NROWS floats
    __bf16* wph = (__bf16*)(nbP + 4 * NROWS);  // 5*16384 bf16
    __bf16* wpl = wph + 5 * 16384;

    prep_kernel<<<40, 256, 0, stream>>>(wq, wk, wv, wg, wo, wph, wpl);
    lnproj_kernel<<<2048, 256, 0, stream>>>(
        act, ln_g, ln_b, w2d, wph, bg, qb, kb, vb, gfh, nbP);
    attn_kernel<<<NRES * 4, 256, 0, stream>>>(
        qb, kb, vb, gfh, mask, nbP, gth, gtl);
    out_kernel<<<1024, 256, 0, stream>>>(gth, gtl, wph, wpl, bo, out);
}